// Round 9
// baseline (941.536 us; speedup 1.0000x reference)
//
#include <hip/hip_runtime.h>
#include <hip/hip_fp16.h>

#define N_NODES 100000
#define N_EDGES 1600000
#define IN_CH   128
#define NHID    64
#define OUT_CH  40
#define NBLK    391    // ceil(N_NODES/256)
#define NBUCK   196    // ceil(N_NODES/512)
#define BCAP    8960   // fixed bucket capacity (mean 8163, +8 sigma)
#define E4CAP   (N_EDGES + 7 * N_NODES + 64)   // padded CSR worst case

// ---------------- rowptr scans (over PADDED counts; dinv from true counts) ----------------

__global__ __launch_bounds__(256) void k_scan1(const int* __restrict__ cnt,
                                               int* __restrict__ rowptr,
                                               int* __restrict__ bsum,
                                               float* __restrict__ dinv) {
    __shared__ int s[256];
    int t = threadIdx.x;
    int n = blockIdx.x * 256 + t;
    int v = (n < N_NODES) ? cnt[n] : 0;
    int pv = (v + 7) & ~7;                  // pad to multiple of 8
    s[t] = pv;
    __syncthreads();
    for (int off = 1; off < 256; off <<= 1) {
        int add = (t >= off) ? s[t - off] : 0;
        __syncthreads();
        s[t] += add;
        __syncthreads();
    }
    int incl = s[t];
    if (n < N_NODES) {
        rowptr[n] = incl - pv;
        dinv[n] = (v > 0) ? rsqrtf((float)v) : 0.0f;
    }
    if (t == 255) bsum[blockIdx.x] = incl;
}

// block-sum scan + degree-bin scan (bins scanned by the same block; all-thread syncs)
__global__ __launch_bounds__(512) void k_scan2(int* __restrict__ bsum,
                                               int* __restrict__ rowptr,
                                               const int* __restrict__ gbins,
                                               int* __restrict__ binCur) {
    __shared__ int s[512];
    __shared__ int sb[64];
    int t = threadIdx.x;
    int v = (t < NBLK) ? bsum[t] : 0;
    s[t] = v;
    if (t < 64) sb[t] = gbins[t];
    __syncthreads();
    for (int off = 1; off < 512; off <<= 1) {
        int add = (t >= off) ? s[t - off] : 0;
        __syncthreads();
        s[t] += add;
        __syncthreads();
    }
    if (t == NBLK - 1) rowptr[N_NODES] = s[t];   // padded grand total
    if (t < NBLK) bsum[t] = s[t] - v;
    for (int off = 1; off < 64; off <<= 1) {
        int add = (t >= off && t < 64) ? sb[t - off] : 0;
        __syncthreads();
        if (t < 64) sb[t] += add;
        __syncthreads();
    }
    if (t < 64) binCur[t] = sb[t] - gbins[t];    // exclusive base per degree bin
}

__global__ __launch_bounds__(256) void k_scan3(const int* __restrict__ bsum,
                                               int* __restrict__ rowptr) {
    int n = blockIdx.x * 256 + threadIdx.x;
    if (n < N_NODES) rowptr[n] = rowptr[n] + bsum[n >> 8];
}

// ---- counting-sort placement: perm = node ids ordered by (clamped) degree ----

__global__ __launch_bounds__(256) void k_place(const int* __restrict__ cnt,
                                               int* __restrict__ binCur,
                                               int* __restrict__ perm) {
    __shared__ int hist[64];
    __shared__ int base[64];
    int t = threadIdx.x;
    int n = blockIdx.x * 256 + t;
    if (t < 64) hist[t] = 0;
    __syncthreads();
    int bin = -1;
    if (n < N_NODES) {
        int d = cnt[n];
        bin = (d < 63) ? d : 63;
        atomicAdd(&hist[bin], 1);
    }
    __syncthreads();
    if (t < 64) {
        int h = hist[t];
        base[t] = h ? atomicAdd(&binCur[t], h) : 0;
        hist[t] = 0;                         // reuse as local cursor
    }
    __syncthreads();
    if (n < N_NODES) {
        int off = atomicAdd(&hist[bin], 1);
        perm[base[bin] + off] = n;
    }
}

// ---- scatter pass A: fixed-capacity buckets by c>>9 (pure bucketing; R5-proven) ----

__global__ __launch_bounds__(256) void k_scatA(const int* __restrict__ ei,
                                               int* __restrict__ bucketCnt,
                                               int2* __restrict__ ebufA) {
    __shared__ int hist[NBUCK];
    __shared__ int base[NBUCK];
    int t = threadIdx.x;
    int chunk = blockIdx.x * 4096;
    for (int i = t; i < NBUCK; i += 256) hist[i] = 0;
    __syncthreads();
#pragma unroll 4
    for (int i = 0; i < 16; i++) {
        int e = chunk + i * 256 + t;
        if (e < N_EDGES) atomicAdd(&hist[ei[N_EDGES + e] >> 9], 1);
    }
    __syncthreads();
    for (int b = t; b < NBUCK; b += 256) {
        int h = hist[b];
        base[b] = h ? atomicAdd(&bucketCnt[b], h) : 0;
    }
    __syncthreads();
#pragma unroll 4
    for (int i = 0; i < 16; i++) {
        int e = chunk + i * 256 + t;
        if (e < N_EDGES) {
            int r = ei[e], c = ei[N_EDGES + e];
            int pos = atomicAdd(&base[c >> 9], 1);
            ebufA[(size_t)(c >> 9) * BCAP + pos] = make_int2(r, c);
        }
    }
}

// ---- degree count from bucketed edges + global degree-bin histogram ----

__global__ __launch_bounds__(256) void k_deg(const int2* __restrict__ ebufA,
                                             const int* __restrict__ bucketCnt,
                                             int* __restrict__ cnt,
                                             int* __restrict__ gbins) {
    __shared__ int hist[512];
    __shared__ int dbins[64];
    int b = blockIdx.x;
    int nodeB = b * 512;
    int t = threadIdx.x;
    for (int i = t; i < 512; i += 256) hist[i] = 0;
    if (t < 64) dbins[t] = 0;
    __syncthreads();
    int nE = bucketCnt[b];
    const int2* src = ebufA + (size_t)b * BCAP;
    for (int i = t; i < nE; i += 256) atomicAdd(&hist[src[i].y - nodeB], 1);
    __syncthreads();
    for (int i = t; i < 512; i += 256) {
        int node = nodeB + i;
        if (node < N_NODES) {
            int h = hist[i];
            cnt[node] = h;
            atomicAdd(&dbins[(h < 63) ? h : 63], 1);
        }
    }
    __syncthreads();
    if (t < 64 && dbins[t]) atomicAdd(&gbins[t], dbins[t]);
}

// ---- scatter pass B: per-NODE cursors -> padded CSR; tail-fill pads with zero row ----

__global__ __launch_bounds__(256) void k_scatB(const int2* __restrict__ ebufA,
                                               const int* __restrict__ bucketCnt,
                                               const int* __restrict__ rowptr,
                                               int* __restrict__ e4) {
    __shared__ int lcur[512];
    int b = blockIdx.x;
    int nodeB = b * 512;
    int t = threadIdx.x;
    for (int i = t; i < 512; i += 256) {
        int node = nodeB + i;
        lcur[i] = (node < N_NODES) ? rowptr[node] : 0;
    }
    __syncthreads();
    int nE = bucketCnt[b];
    const int2* src = ebufA + (size_t)b * BCAP;
    for (int i = t; i < nE; i += 256) {
        int2 rc = src[i];
        int pos = atomicAdd(&lcur[rc.y - nodeB], 1);
        e4[pos] = rc.x;
    }
    __syncthreads();
    for (int i = t; i < 512; i += 256) {
        int node = nodeB + i;
        if (node < N_NODES) {
            int end = rowptr[node + 1];
            for (int pos = lcur[i]; pos < end; pos++) e4[pos] = N_NODES;
        }
    }
}

// ---- pack 4 floats -> 4 halves (8B) ----
__device__ __forceinline__ void store_h4(__half* dst, float a, float b, float c, float d) {
    union { uint2 u; __half2 h[2]; } pk;
    pk.h[0] = __floats2half2_rn(a, b);
    pk.h[1] = __floats2half2_rn(c, d);
    *(uint2*)dst = pk.u;
}

// ---------------- fc1: retiled (nodes on ty, channels on tx) + W in LDS ----------------

__global__ __launch_bounds__(256, 2) void k_fc1(const float* __restrict__ x,
                                                const float* __restrict__ w,
                                                const float* __restrict__ b,
                                                const float* __restrict__ dinv,
                                                __half* __restrict__ h016,
                                                __half* __restrict__ hs1) {
    __shared__ float xs[64 * 128];     // [node row][f4idx ^ swz]
    __shared__ float wL[64 * 128];     // [out ch row][f4idx ^ swz]
    int t = threadIdx.x;
    int nodeBase = blockIdx.x * 64;

    {
        int lane8 = t & 7, rhalf = t >> 3;     // 32 rows per pass
#pragma unroll
        for (int r2 = 0; r2 < 2; r2++) {
            int nl = r2 * 32 + rhalf;
            int swz = (nl ^ (nl >> 3)) & 7;
            int n = nodeBase + nl;
            float4* dstrow = (float4*)(xs + nl * 128);
            if (n < N_NODES) {
                const float4* src = (const float4*)(x + (size_t)n * IN_CH);
#pragma unroll
                for (int q = 0; q < 4; q++) dstrow[(q * 8 + lane8) ^ swz] = src[q * 8 + lane8];
            } else {
                float4 z = {0.f, 0.f, 0.f, 0.f};
#pragma unroll
                for (int q = 0; q < 4; q++) dstrow[(q * 8 + lane8) ^ swz] = z;
            }
            float4* dstw = (float4*)(wL + nl * 128);
            const float4* srcw = (const float4*)(w + (size_t)nl * IN_CH);
#pragma unroll
            for (int q = 0; q < 4; q++) dstw[(q * 8 + lane8) ^ swz] = srcw[q * 8 + lane8];
        }
    }
    __syncthreads();

    int tx = t & 15, ty = t >> 4;
    int o0 = tx * 4, n0 = ty * 4;     // nodes on ty, channels on tx
    int swzA0 = ((n0 + 0) ^ ((n0 + 0) >> 3)) & 7;
    int swzA1 = ((n0 + 1) ^ ((n0 + 1) >> 3)) & 7;
    int swzA2 = ((n0 + 2) ^ ((n0 + 2) >> 3)) & 7;
    int swzA3 = ((n0 + 3) ^ ((n0 + 3) >> 3)) & 7;
    int swzW0 = ((o0 + 0) ^ ((o0 + 0) >> 3)) & 7;
    int swzW1 = ((o0 + 1) ^ ((o0 + 1) >> 3)) & 7;
    int swzW2 = ((o0 + 2) ^ ((o0 + 2) >> 3)) & 7;
    int swzW3 = ((o0 + 3) ^ ((o0 + 3) >> 3)) & 7;
    const float4* ar0 = (const float4*)(xs + (n0 + 0) * 128);
    const float4* ar1 = (const float4*)(xs + (n0 + 1) * 128);
    const float4* ar2 = (const float4*)(xs + (n0 + 2) * 128);
    const float4* ar3 = (const float4*)(xs + (n0 + 3) * 128);
    const float4* wr0 = (const float4*)(wL + (o0 + 0) * 128);
    const float4* wr1 = (const float4*)(wL + (o0 + 1) * 128);
    const float4* wr2 = (const float4*)(wL + (o0 + 2) * 128);
    const float4* wr3 = (const float4*)(wL + (o0 + 3) * 128);

    float c[4][4];
#pragma unroll
    for (int i = 0; i < 4; i++)
#pragma unroll
        for (int j = 0; j < 4; j++) c[i][j] = 0.f;

#pragma unroll 4
    for (int k = 0; k < IN_CH; k += 4) {
        int kk = k >> 2;
        float4 b0 = wr0[kk ^ swzW0];
        float4 b1 = wr1[kk ^ swzW1];
        float4 b2 = wr2[kk ^ swzW2];
        float4 b3 = wr3[kk ^ swzW3];
        float4 a0 = ar0[kk ^ swzA0];
        float4 a1 = ar1[kk ^ swzA1];
        float4 a2 = ar2[kk ^ swzA2];
        float4 a3 = ar3[kk ^ swzA3];
#pragma unroll
        for (int i = 0; i < 4; i++) {
            float4 a = (i == 0) ? a0 : (i == 1) ? a1 : (i == 2) ? a2 : a3;
            c[i][0] = fmaf(a.x, b0.x, fmaf(a.y, b0.y, fmaf(a.z, b0.z, fmaf(a.w, b0.w, c[i][0]))));
            c[i][1] = fmaf(a.x, b1.x, fmaf(a.y, b1.y, fmaf(a.z, b1.z, fmaf(a.w, b1.w, c[i][1]))));
            c[i][2] = fmaf(a.x, b2.x, fmaf(a.y, b2.y, fmaf(a.z, b2.z, fmaf(a.w, b2.w, c[i][2]))));
            c[i][3] = fmaf(a.x, b3.x, fmaf(a.y, b3.y, fmaf(a.z, b3.z, fmaf(a.w, b3.w, c[i][3]))));
        }
    }

    float4 bias = *(const float4*)&b[o0];
#pragma unroll
    for (int i = 0; i < 4; i++) {
        int n = nodeBase + n0 + i;
        if (n < N_NODES) {
            float vx = fmaxf(c[i][0] + bias.x, 0.f);
            float vy = fmaxf(c[i][1] + bias.y, 0.f);
            float vz = fmaxf(c[i][2] + bias.z, 0.f);
            float vw = fmaxf(c[i][3] + bias.w, 0.f);
            store_h4(&h016[(size_t)n * NHID + o0], vx, vy, vz, vw);
            float dn = dinv[n];
            store_h4(&hs1[(size_t)n * NHID + o0], vx * dn, vy * dn, vz * dn, vw * dn);
        }
    }
}

// ------- fused GCN2Conv layer: wave-autonomous + DEGREE-SORTED node assignment -------

__global__ __launch_bounds__(256, 8) void k_conv(const __half* __restrict__ hs,
                                                 const __half* __restrict__ h0,
                                                 const int* __restrict__ rowptr,
                                                 const int* __restrict__ e4,
                                                 const float* __restrict__ W,   // [c][o] 64x64
                                                 const float* __restrict__ dinv,
                                                 const int* __restrict__ perm,
                                                 __half* __restrict__ hout,
                                                 int scaled) {
    __shared__ float mixs[4][8 * 68];
    int t = threadIdx.x;
    int wid = t >> 6, lane = t & 63;
    int wslot = blockIdx.x * 32 + wid * 8;   // 8 perm slots per wave
    int grp = lane >> 3;                     // 8 groups of 8 lanes -> 1 node each
    int cg = (lane & 7) * 8;                 // 8 channels per lane
    float* mix = mixs[wid];

    int n = perm[wslot + grp];
    int s = rowptr[n], e = rowptr[n + 1];    // e-s is a multiple of 8

#define ISSUE(pv, pm)                                                    \
    {                                                                    \
        pv[0] = *(const float4*)&hs[(size_t)pm.x * NHID + cg];           \
        pv[1] = *(const float4*)&hs[(size_t)pm.y * NHID + cg];           \
        pv[2] = *(const float4*)&hs[(size_t)pm.z * NHID + cg];           \
        pv[3] = *(const float4*)&hs[(size_t)pm.w * NHID + cg];           \
    }
#define ACC4(cv)                                                         \
    {                                                                    \
        _Pragma("unroll")                                                \
        for (int u = 0; u < 4; u++) {                                    \
            const __half2* hp = (const __half2*)&cv[u];                  \
            _Pragma("unroll")                                            \
            for (int q = 0; q < 4; q++) {                                \
                float2 f = __half22float2(hp[q]);                        \
                acc[q * 2 + 0] += f.x;                                   \
                acc[q * 2 + 1] += f.y;                                   \
            }                                                            \
        }                                                                \
    }

    int4   pmA, pmB;
    float4 pvA[4], pvB[4];
    if (e > s) {                              // deg >= 8 when nonzero (padded)
        pmA = *(const int4*)&e4[s];
        ISSUE(pvA, pmA);
        pmB = *(const int4*)&e4[s + 4];
        ISSUE(pvB, pmB);
    }

    float dn = dinv[n];
    float4 h0raw = *(const float4*)&h0[(size_t)n * NHID + cg];   // 8 halves

    float acc[8];
#pragma unroll
    for (int i = 0; i < 8; i++) acc[i] = 0.f;

    for (int j = s; j < e; j += 8) {
        {
            float4 cv[4];
#pragma unroll
            for (int u = 0; u < 4; u++) cv[u] = pvA[u];
            int jn = j + 8;
            if (jn < e) { pmA = *(const int4*)&e4[jn]; ISSUE(pvA, pmA); }
            ACC4(cv);
        }
        {
            float4 cv[4];
#pragma unroll
            for (int u = 0; u < 4; u++) cv[u] = pvB[u];
            int jn = j + 12;
            if (jn < e) { pmB = *(const int4*)&e4[jn]; ISSUE(pvB, pmB); }
            ACC4(cv);
        }
    }
#undef ISSUE
#undef ACC4

    {
        const __half* h0h = (const __half*)&h0raw;
        float a = 0.9f * dn;
        float m[8];
#pragma unroll
        for (int q = 0; q < 8; q++)
            m[q] = fmaf(a, acc[q], 0.1f * __half2float(h0h[q]));
        float4 m0 = {m[0], m[1], m[2], m[3]};
        float4 m1 = {m[4], m[5], m[6], m[7]};
        *(float4*)&mix[grp * 68 + cg] = m0;
        *(float4*)&mix[grp * 68 + cg + 4] = m1;
    }
    __threadfence_block();   // mix visible within wave

    // per-wave GEMM 8x64, 2x4 acc per lane; W rows broadcast via L1; fp16 output
    int tx = lane & 15, ty = lane >> 4;
    int o0 = tx * 4, r0 = ty * 2;
    float c[2][4];
#pragma unroll
    for (int i = 0; i < 2; i++)
#pragma unroll
        for (int j = 0; j < 4; j++) c[i][j] = 0.f;

#pragma unroll 4
    for (int k = 0; k < NHID; k += 4) {
        float4 b0 = *(const float4*)&W[(k + 0) * NHID + o0];
        float4 b1 = *(const float4*)&W[(k + 1) * NHID + o0];
        float4 b2 = *(const float4*)&W[(k + 2) * NHID + o0];
        float4 b3 = *(const float4*)&W[(k + 3) * NHID + o0];
#pragma unroll
        for (int i = 0; i < 2; i++) {
            float4 a = *(const float4*)&mix[(r0 + i) * 68 + k];
            c[i][0] = fmaf(a.x, b0.x, fmaf(a.y, b1.x, fmaf(a.z, b2.x, fmaf(a.w, b3.x, c[i][0]))));
            c[i][1] = fmaf(a.x, b0.y, fmaf(a.y, b1.y, fmaf(a.z, b2.y, fmaf(a.w, b3.y, c[i][1]))));
            c[i][2] = fmaf(a.x, b0.z, fmaf(a.y, b1.z, fmaf(a.z, b2.z, fmaf(a.w, b3.z, c[i][2]))));
            c[i][3] = fmaf(a.x, b0.w, fmaf(a.y, b1.w, fmaf(a.z, b2.w, fmaf(a.w, b3.w, c[i][3]))));
        }
    }
#pragma unroll
    for (int i = 0; i < 2; i++) {
        int n2 = perm[wslot + r0 + i];
        float sc = 1.0f;
        if (scaled) sc = dinv[n2];
        store_h4(&hout[(size_t)n2 * NHID + o0],
                 fmaxf(c[i][0], 0.f) * sc, fmaxf(c[i][1], 0.f) * sc,
                 fmaxf(c[i][2], 0.f) * sc, fmaxf(c[i][3], 0.f) * sc);
    }
}

// ---------------- fc2: out = h @ fc2_w^T + b (h in fp16) ----------------

__global__ __launch_bounds__(256) void k_fc2(const __half* __restrict__ h,
                                             const float* __restrict__ w,
                                             const float* __restrict__ b,
                                             float* __restrict__ out) {
    __shared__ float wT[NHID * 44];
    __shared__ float hsl[64 * 68];
    int t = threadIdx.x;
    int nodeBase = blockIdx.x * 64;

    for (int id = t; id < NHID * OUT_CH; id += 256) {
        int o = id >> 6, k = id & 63;
        wT[k * 44 + o] = w[id];
    }
    {
        int nl = t >> 2, seg = t & 3;
        int n = nodeBase + nl;
        float* dst = hsl + nl * 68 + seg * 16;
        if (n < N_NODES) {
            float4 raw0 = *(const float4*)&h[(size_t)n * NHID + seg * 16];
            float4 raw1 = *(const float4*)&h[(size_t)n * NHID + seg * 16 + 8];
            const __half2* hp0 = (const __half2*)&raw0;
            const __half2* hp1 = (const __half2*)&raw1;
#pragma unroll
            for (int q = 0; q < 4; q++) {
                float2 f = __half22float2(hp0[q]);
                dst[q * 2 + 0] = f.x;
                dst[q * 2 + 1] = f.y;
            }
#pragma unroll
            for (int q = 0; q < 4; q++) {
                float2 f = __half22float2(hp1[q]);
                dst[8 + q * 2 + 0] = f.x;
                dst[8 + q * 2 + 1] = f.y;
            }
        } else {
#pragma unroll
            for (int q = 0; q < 16; q++) dst[q] = 0.f;
        }
    }
    __syncthreads();

    if (t < 160) {
        int tx = t % 10, ty = t / 10;
        int o0 = tx * 4, n0 = ty * 4;
        float c[4][4];
#pragma unroll
        for (int i = 0; i < 4; i++)
#pragma unroll
            for (int j = 0; j < 4; j++) c[i][j] = 0.f;

#pragma unroll 4
        for (int k = 0; k < NHID; k += 4) {
            float4 b0 = *(const float4*)&wT[(k + 0) * 44 + o0];
            float4 b1 = *(const float4*)&wT[(k + 1) * 44 + o0];
            float4 b2 = *(const float4*)&wT[(k + 2) * 44 + o0];
            float4 b3 = *(const float4*)&wT[(k + 3) * 44 + o0];
#pragma unroll
            for (int i = 0; i < 4; i++) {
                float4 a = *(const float4*)&hsl[(n0 + i) * 68 + k];
                c[i][0] = fmaf(a.x, b0.x, fmaf(a.y, b1.x, fmaf(a.z, b2.x, fmaf(a.w, b3.x, c[i][0]))));
                c[i][1] = fmaf(a.x, b0.y, fmaf(a.y, b1.y, fmaf(a.z, b2.y, fmaf(a.w, b3.y, c[i][1]))));
                c[i][2] = fmaf(a.x, b0.z, fmaf(a.y, b1.z, fmaf(a.z, b2.z, fmaf(a.w, b3.z, c[i][2]))));
                c[i][3] = fmaf(a.x, b0.w, fmaf(a.y, b1.w, fmaf(a.z, b2.w, fmaf(a.w, b3.w, c[i][3]))));
            }
        }
        float4 bias = *(const float4*)&b[o0];
#pragma unroll
        for (int i = 0; i < 4; i++) {
            int n = nodeBase + n0 + i;
            if (n < N_NODES) {
                float4 v;
                v.x = c[i][0] + bias.x;
                v.y = c[i][1] + bias.y;
                v.z = c[i][2] + bias.z;
                v.w = c[i][3] + bias.w;
                *(float4*)&out[(size_t)n * OUT_CH + o0] = v;
            }
        }
    }
}

// ---------------- launch ----------------

extern "C" void kernel_launch(void* const* d_in, const int* in_sizes, int n_in,
                              void* d_out, int out_size, void* d_ws, size_t ws_size,
                              hipStream_t stream) {
    const float* x    = (const float*)d_in[0];
    const int*   ei   = (const int*)d_in[1];
    const float* fc1w = (const float*)d_in[3];
    const float* fc1b = (const float*)d_in[4];
    const float* cw   = (const float*)d_in[5];
    const float* fc2w = (const float*)d_in[6];
    const float* fc2b = (const float*)d_in[7];
    float* out = (float*)d_out;

    char* p = (char*)d_ws;
    auto alloc = [&](size_t bytes) { char* r = p; p += (bytes + 255) & ~(size_t)255; return r; };
    __half* h016   = (__half*)alloc((size_t)N_NODES * NHID * 2);
    __half* hsA    = (__half*)alloc((size_t)(N_NODES + 1) * NHID * 2);   // +1 zero row
    __half* hsB    = (__half*)alloc((size_t)(N_NODES + 1) * NHID * 2);   // +1 zero row
    int*    e4     = (int*)   alloc((size_t)E4CAP * 4);                  // padded CSR
    int2*   ebufA  = (int2*)  alloc((size_t)NBUCK * BCAP * 8);   // 14.05 MB; reused as h4 buffer
    int*    cnt    = (int*)   alloc((size_t)N_NODES * 4);
    int*    rowptr = (int*)   alloc((size_t)(N_NODES + 1) * 4);
    int*    perm   = (int*)   alloc((size_t)N_NODES * 4);
    int*    bCnt   = (int*)   alloc((size_t)NBUCK * 4);
    float*  dinv   = (float*) alloc((size_t)N_NODES * 4);
    int*    bsum   = (int*)   alloc(512 * 4);
    int*    gbins  = (int*)   alloc(64 * 4);
    int*    binCur = (int*)   alloc(64 * 4);
    __half* h4     = (__half*)ebufA;    // layer-4 unscaled output (after scatB consumed ebufA)

    hipMemsetAsync(bCnt, 0, (size_t)NBUCK * 4, stream);
    hipMemsetAsync(gbins, 0, 64 * 4, stream);
    hipMemsetAsync(hsA + (size_t)N_NODES * NHID, 0, NHID * 2, stream);
    hipMemsetAsync(hsB + (size_t)N_NODES * NHID, 0, NHID * 2, stream);

    k_scatA<<<(N_EDGES + 4095) / 4096, 256, 0, stream>>>(ei, bCnt, ebufA);
    k_deg  <<<NBUCK, 256, 0, stream>>>(ebufA, bCnt, cnt, gbins);
    k_scan1<<<NBLK, 256, 0, stream>>>(cnt, rowptr, bsum, dinv);
    k_scan2<<<1, 512, 0, stream>>>(bsum, rowptr, gbins, binCur);
    k_scan3<<<NBLK, 256, 0, stream>>>(bsum, rowptr);
    k_place<<<NBLK, 256, 0, stream>>>(cnt, binCur, perm);
    k_scatB<<<NBUCK, 256, 0, stream>>>(ebufA, bCnt, rowptr, e4);

    int gb64 = (N_NODES + 63) / 64;   // 1563
    int gb32 = N_NODES / 32;          // 3125
    k_fc1 <<<gb64, 256, 0, stream>>>(x, fc1w, fc1b, dinv, h016, hsA);
    k_conv<<<gb32, 256, 0, stream>>>(hsA, h016, rowptr, e4, cw + 0 * NHID * NHID, dinv, perm, hsB, 1);
    k_conv<<<gb32, 256, 0, stream>>>(hsB, h016, rowptr, e4, cw + 1 * NHID * NHID, dinv, perm, hsA, 1);
    k_conv<<<gb32, 256, 0, stream>>>(hsA, h016, rowptr, e4, cw + 2 * NHID * NHID, dinv, perm, hsB, 1);
    k_conv<<<gb32, 256, 0, stream>>>(hsB, h016, rowptr, e4, cw + 3 * NHID * NHID, dinv, perm, h4, 0);
    k_fc2 <<<gb64, 256, 0, stream>>>(h4, fc2w, fc2b, out);
}

// Round 10
// 931.905 us; speedup vs baseline: 1.0103x; 1.0103x over previous
//
#include <hip/hip_runtime.h>
#include <hip/hip_fp16.h>

#define N_NODES 100000
#define N_EDGES 1600000
#define IN_CH   128
#define NHID    64
#define OUT_CH  40
#define NBLK    391    // ceil(N_NODES/256)
#define NBUCK   196    // ceil(N_NODES/512)
#define BCAP    8960   // fixed bucket capacity (mean 8163, +8 sigma)
#define E4CAP   (N_EDGES + 7 * N_NODES + 64)   // padded CSR worst case

// ---------------- rowptr scans (over PADDED counts; dinv from true counts) ----------------

__global__ __launch_bounds__(256) void k_scan1(const int* __restrict__ cnt,
                                               int* __restrict__ rowptr,
                                               int* __restrict__ bsum,
                                               float* __restrict__ dinv) {
    __shared__ int s[256];
    int t = threadIdx.x;
    int n = blockIdx.x * 256 + t;
    int v = (n < N_NODES) ? cnt[n] : 0;
    int pv = (v + 7) & ~7;                  // pad to multiple of 8
    s[t] = pv;
    __syncthreads();
    for (int off = 1; off < 256; off <<= 1) {
        int add = (t >= off) ? s[t - off] : 0;
        __syncthreads();
        s[t] += add;
        __syncthreads();
    }
    int incl = s[t];
    if (n < N_NODES) {
        rowptr[n] = incl - pv;
        dinv[n] = (v > 0) ? rsqrtf((float)v) : 0.0f;
    }
    if (t == 255) bsum[blockIdx.x] = incl;
}

__global__ __launch_bounds__(512) void k_scan2(int* __restrict__ bsum,
                                               int* __restrict__ rowptr) {
    __shared__ int s[512];
    int t = threadIdx.x;
    int v = (t < NBLK) ? bsum[t] : 0;
    s[t] = v;
    __syncthreads();
    for (int off = 1; off < 512; off <<= 1) {
        int add = (t >= off) ? s[t - off] : 0;
        __syncthreads();
        s[t] += add;
        __syncthreads();
    }
    if (t == NBLK - 1) rowptr[N_NODES] = s[t];   // padded grand total
    if (t < NBLK) bsum[t] = s[t] - v;
}

__global__ __launch_bounds__(256) void k_scan3(const int* __restrict__ bsum,
                                               int* __restrict__ rowptr) {
    int n = blockIdx.x * 256 + threadIdx.x;
    if (n < N_NODES) rowptr[n] = rowptr[n] + bsum[n >> 8];
}

// ---- BLOCK-LOCAL degree sort: rank the 32 nodes of each conv window ----
// perm[g0 + rank] = n, rank = #{j in window : deg[j] < deg[n] or (== and j<n)}.
// Bijective within the window; preserves all R7 memory locality (perm stays
// inside the same 32-node window). No atomics, deterministic. N_NODES%32==0.

__global__ __launch_bounds__(256) void k_place32(const int* __restrict__ cnt,
                                                 int* __restrict__ perm) {
    int n = blockIdx.x * 256 + threadIdx.x;
    if (n < N_NODES) {
        int g0 = n & ~31;
        int dn = cnt[n];
        int rank = 0;
#pragma unroll 8
        for (int j = 0; j < 32; j++) {
            int dj = cnt[g0 + j];
            rank += (dj < dn || (dj == dn && (g0 + j) < n)) ? 1 : 0;
        }
        perm[g0 + rank] = n;
    }
}

// ---- scatter pass A: fixed-capacity buckets by c>>9 (pure bucketing; R5-proven) ----

__global__ __launch_bounds__(256) void k_scatA(const int* __restrict__ ei,
                                               int* __restrict__ bucketCnt,
                                               int2* __restrict__ ebufA) {
    __shared__ int hist[NBUCK];
    __shared__ int base[NBUCK];
    int t = threadIdx.x;
    int chunk = blockIdx.x * 4096;
    for (int i = t; i < NBUCK; i += 256) hist[i] = 0;
    __syncthreads();
#pragma unroll 4
    for (int i = 0; i < 16; i++) {
        int e = chunk + i * 256 + t;
        if (e < N_EDGES) atomicAdd(&hist[ei[N_EDGES + e] >> 9], 1);
    }
    __syncthreads();
    for (int b = t; b < NBUCK; b += 256) {
        int h = hist[b];
        base[b] = h ? atomicAdd(&bucketCnt[b], h) : 0;
    }
    __syncthreads();
#pragma unroll 4
    for (int i = 0; i < 16; i++) {
        int e = chunk + i * 256 + t;
        if (e < N_EDGES) {
            int r = ei[e], c = ei[N_EDGES + e];
            int pos = atomicAdd(&base[c >> 9], 1);
            ebufA[(size_t)(c >> 9) * BCAP + pos] = make_int2(r, c);
        }
    }
}

// ---- degree count from bucketed edges: contiguous read, LDS histogram ----

__global__ __launch_bounds__(256) void k_deg(const int2* __restrict__ ebufA,
                                             const int* __restrict__ bucketCnt,
                                             int* __restrict__ cnt) {
    __shared__ int hist[512];
    int b = blockIdx.x;
    int nodeB = b * 512;
    int t = threadIdx.x;
    for (int i = t; i < 512; i += 256) hist[i] = 0;
    __syncthreads();
    int nE = bucketCnt[b];
    const int2* src = ebufA + (size_t)b * BCAP;
    for (int i = t; i < nE; i += 256) atomicAdd(&hist[src[i].y - nodeB], 1);
    __syncthreads();
    for (int i = t; i < 512; i += 256) {
        int node = nodeB + i;
        if (node < N_NODES) cnt[node] = hist[i];
    }
}

// ---- scatter pass B: per-NODE cursors -> padded CSR; tail-fill pads with zero row ----

__global__ __launch_bounds__(256) void k_scatB(const int2* __restrict__ ebufA,
                                               const int* __restrict__ bucketCnt,
                                               const int* __restrict__ rowptr,
                                               int* __restrict__ e4) {
    __shared__ int lcur[512];
    int b = blockIdx.x;
    int nodeB = b * 512;
    int t = threadIdx.x;
    for (int i = t; i < 512; i += 256) {
        int node = nodeB + i;
        lcur[i] = (node < N_NODES) ? rowptr[node] : 0;
    }
    __syncthreads();
    int nE = bucketCnt[b];
    const int2* src = ebufA + (size_t)b * BCAP;
    for (int i = t; i < nE; i += 256) {
        int2 rc = src[i];
        int pos = atomicAdd(&lcur[rc.y - nodeB], 1);
        e4[pos] = rc.x;
    }
    __syncthreads();
    for (int i = t; i < 512; i += 256) {
        int node = nodeB + i;
        if (node < N_NODES) {
            int end = rowptr[node + 1];
            for (int pos = lcur[i]; pos < end; pos++) e4[pos] = N_NODES;
        }
    }
}

// ---- pack 4 floats -> 4 halves (8B) ----
__device__ __forceinline__ void store_h4(__half* dst, float a, float b, float c, float d) {
    union { uint2 u; __half2 h[2]; } pk;
    pk.h[0] = __floats2half2_rn(a, b);
    pk.h[1] = __floats2half2_rn(c, d);
    *(uint2*)dst = pk.u;
}

// ---------------- fc1: retiled (nodes on ty, channels on tx) + W in LDS ----------------

__global__ __launch_bounds__(256, 2) void k_fc1(const float* __restrict__ x,
                                                const float* __restrict__ w,
                                                const float* __restrict__ b,
                                                const float* __restrict__ dinv,
                                                __half* __restrict__ h016,
                                                __half* __restrict__ hs1) {
    __shared__ float xs[64 * 128];     // [node row][f4idx ^ swz]
    __shared__ float wL[64 * 128];     // [out ch row][f4idx ^ swz]
    int t = threadIdx.x;
    int nodeBase = blockIdx.x * 64;

    {
        int lane8 = t & 7, rhalf = t >> 3;     // 32 rows per pass
#pragma unroll
        for (int r2 = 0; r2 < 2; r2++) {
            int nl = r2 * 32 + rhalf;
            int swz = (nl ^ (nl >> 3)) & 7;
            int n = nodeBase + nl;
            float4* dstrow = (float4*)(xs + nl * 128);
            if (n < N_NODES) {
                const float4* src = (const float4*)(x + (size_t)n * IN_CH);
#pragma unroll
                for (int q = 0; q < 4; q++) dstrow[(q * 8 + lane8) ^ swz] = src[q * 8 + lane8];
            } else {
                float4 z = {0.f, 0.f, 0.f, 0.f};
#pragma unroll
                for (int q = 0; q < 4; q++) dstrow[(q * 8 + lane8) ^ swz] = z;
            }
            float4* dstw = (float4*)(wL + nl * 128);
            const float4* srcw = (const float4*)(w + (size_t)nl * IN_CH);
#pragma unroll
            for (int q = 0; q < 4; q++) dstw[(q * 8 + lane8) ^ swz] = srcw[q * 8 + lane8];
        }
    }
    __syncthreads();

    int tx = t & 15, ty = t >> 4;
    int o0 = tx * 4, n0 = ty * 4;     // nodes on ty, channels on tx
    int swzA0 = ((n0 + 0) ^ ((n0 + 0) >> 3)) & 7;
    int swzA1 = ((n0 + 1) ^ ((n0 + 1) >> 3)) & 7;
    int swzA2 = ((n0 + 2) ^ ((n0 + 2) >> 3)) & 7;
    int swzA3 = ((n0 + 3) ^ ((n0 + 3) >> 3)) & 7;
    int swzW0 = ((o0 + 0) ^ ((o0 + 0) >> 3)) & 7;
    int swzW1 = ((o0 + 1) ^ ((o0 + 1) >> 3)) & 7;
    int swzW2 = ((o0 + 2) ^ ((o0 + 2) >> 3)) & 7;
    int swzW3 = ((o0 + 3) ^ ((o0 + 3) >> 3)) & 7;
    const float4* ar0 = (const float4*)(xs + (n0 + 0) * 128);
    const float4* ar1 = (const float4*)(xs + (n0 + 1) * 128);
    const float4* ar2 = (const float4*)(xs + (n0 + 2) * 128);
    const float4* ar3 = (const float4*)(xs + (n0 + 3) * 128);
    const float4* wr0 = (const float4*)(wL + (o0 + 0) * 128);
    const float4* wr1 = (const float4*)(wL + (o0 + 1) * 128);
    const float4* wr2 = (const float4*)(wL + (o0 + 2) * 128);
    const float4* wr3 = (const float4*)(wL + (o0 + 3) * 128);

    float c[4][4];
#pragma unroll
    for (int i = 0; i < 4; i++)
#pragma unroll
        for (int j = 0; j < 4; j++) c[i][j] = 0.f;

#pragma unroll 4
    for (int k = 0; k < IN_CH; k += 4) {
        int kk = k >> 2;
        float4 b0 = wr0[kk ^ swzW0];
        float4 b1 = wr1[kk ^ swzW1];
        float4 b2 = wr2[kk ^ swzW2];
        float4 b3 = wr3[kk ^ swzW3];
        float4 a0 = ar0[kk ^ swzA0];
        float4 a1 = ar1[kk ^ swzA1];
        float4 a2 = ar2[kk ^ swzA2];
        float4 a3 = ar3[kk ^ swzA3];
#pragma unroll
        for (int i = 0; i < 4; i++) {
            float4 a = (i == 0) ? a0 : (i == 1) ? a1 : (i == 2) ? a2 : a3;
            c[i][0] = fmaf(a.x, b0.x, fmaf(a.y, b0.y, fmaf(a.z, b0.z, fmaf(a.w, b0.w, c[i][0]))));
            c[i][1] = fmaf(a.x, b1.x, fmaf(a.y, b1.y, fmaf(a.z, b1.z, fmaf(a.w, b1.w, c[i][1]))));
            c[i][2] = fmaf(a.x, b2.x, fmaf(a.y, b2.y, fmaf(a.z, b2.z, fmaf(a.w, b2.w, c[i][2]))));
            c[i][3] = fmaf(a.x, b3.x, fmaf(a.y, b3.y, fmaf(a.z, b3.z, fmaf(a.w, b3.w, c[i][3]))));
        }
    }

    float4 bias = *(const float4*)&b[o0];
#pragma unroll
    for (int i = 0; i < 4; i++) {
        int n = nodeBase + n0 + i;
        if (n < N_NODES) {
            float vx = fmaxf(c[i][0] + bias.x, 0.f);
            float vy = fmaxf(c[i][1] + bias.y, 0.f);
            float vz = fmaxf(c[i][2] + bias.z, 0.f);
            float vw = fmaxf(c[i][3] + bias.w, 0.f);
            store_h4(&h016[(size_t)n * NHID + o0], vx, vy, vz, vw);
            float dn = dinv[n];
            store_h4(&hs1[(size_t)n * NHID + o0], vx * dn, vy * dn, vz * dn, vw * dn);
        }
    }
}

// ------- fused GCN2Conv layer: wave-autonomous + BLOCK-LOCAL degree-sorted waves -------
// perm is a within-32-window permutation: wave w gets 8 degree-adjacent nodes of
// ITS OWN block window -> R7 memory locality (same e4/h0/hout lines), but the
// wave's padded edge walk runs to the max of 8 near-equal degrees (~20 vs ~24).
// Metas read as one aligned int4 per batch (rowptr multiples of 8).

__global__ __launch_bounds__(256, 8) void k_conv(const __half* __restrict__ hs,
                                                 const __half* __restrict__ h0,
                                                 const int* __restrict__ rowptr,
                                                 const int* __restrict__ e4,
                                                 const float* __restrict__ W,   // [c][o] 64x64
                                                 const float* __restrict__ dinv,
                                                 const int* __restrict__ perm,
                                                 __half* __restrict__ hout,
                                                 int scaled) {
    __shared__ float mixs[4][8 * 68];
    int t = threadIdx.x;
    int wid = t >> 6, lane = t & 63;
    int wslot = blockIdx.x * 32 + wid * 8;   // 8 perm slots per wave (within block window)
    int grp = lane >> 3;                     // 8 groups of 8 lanes -> 1 node each
    int cg = (lane & 7) * 8;                 // 8 channels per lane
    float* mix = mixs[wid];

    int n = perm[wslot + grp];
    int s = rowptr[n], e = rowptr[n + 1];    // e-s is a multiple of 8

#define ISSUE(pv, pm)                                                    \
    {                                                                    \
        pv[0] = *(const float4*)&hs[(size_t)pm.x * NHID + cg];           \
        pv[1] = *(const float4*)&hs[(size_t)pm.y * NHID + cg];           \
        pv[2] = *(const float4*)&hs[(size_t)pm.z * NHID + cg];           \
        pv[3] = *(const float4*)&hs[(size_t)pm.w * NHID + cg];           \
    }
#define ACC4(cv)                                                         \
    {                                                                    \
        _Pragma("unroll")                                                \
        for (int u = 0; u < 4; u++) {                                    \
            const __half2* hp = (const __half2*)&cv[u];                  \
            _Pragma("unroll")                                            \
            for (int q = 0; q < 4; q++) {                                \
                float2 f = __half22float2(hp[q]);                        \
                acc[q * 2 + 0] += f.x;                                   \
                acc[q * 2 + 1] += f.y;                                   \
            }                                                            \
        }                                                                \
    }

    int4   pmA, pmB;
    float4 pvA[4], pvB[4];
    if (e > s) {                              // deg >= 8 when nonzero (padded)
        pmA = *(const int4*)&e4[s];
        ISSUE(pvA, pmA);
        pmB = *(const int4*)&e4[s + 4];
        ISSUE(pvB, pmB);
    }

    float dn = dinv[n];
    float4 h0raw = *(const float4*)&h0[(size_t)n * NHID + cg];   // 8 halves

    float acc[8];
#pragma unroll
    for (int i = 0; i < 8; i++) acc[i] = 0.f;

    for (int j = s; j < e; j += 8) {
        {
            float4 cv[4];
#pragma unroll
            for (int u = 0; u < 4; u++) cv[u] = pvA[u];
            int jn = j + 8;
            if (jn < e) { pmA = *(const int4*)&e4[jn]; ISSUE(pvA, pmA); }
            ACC4(cv);
        }
        {
            float4 cv[4];
#pragma unroll
            for (int u = 0; u < 4; u++) cv[u] = pvB[u];
            int jn = j + 12;
            if (jn < e) { pmB = *(const int4*)&e4[jn]; ISSUE(pvB, pmB); }
            ACC4(cv);
        }
    }
#undef ISSUE
#undef ACC4

    {
        const __half* h0h = (const __half*)&h0raw;
        float a = 0.9f * dn;
        float m[8];
#pragma unroll
        for (int q = 0; q < 8; q++)
            m[q] = fmaf(a, acc[q], 0.1f * __half2float(h0h[q]));
        float4 m0 = {m[0], m[1], m[2], m[3]};
        float4 m1 = {m[4], m[5], m[6], m[7]};
        *(float4*)&mix[grp * 68 + cg] = m0;
        *(float4*)&mix[grp * 68 + cg + 4] = m1;
    }
    __threadfence_block();   // mix visible within wave

    // per-wave GEMM 8x64, 2x4 acc per lane; W rows broadcast via L1; fp16 output
    int tx = lane & 15, ty = lane >> 4;
    int o0 = tx * 4, r0 = ty * 2;
    float c[2][4];
#pragma unroll
    for (int i = 0; i < 2; i++)
#pragma unroll
        for (int j = 0; j < 4; j++) c[i][j] = 0.f;

#pragma unroll 4
    for (int k = 0; k < NHID; k += 4) {
        float4 b0 = *(const float4*)&W[(k + 0) * NHID + o0];
        float4 b1 = *(const float4*)&W[(k + 1) * NHID + o0];
        float4 b2 = *(const float4*)&W[(k + 2) * NHID + o0];
        float4 b3 = *(const float4*)&W[(k + 3) * NHID + o0];
#pragma unroll
        for (int i = 0; i < 2; i++) {
            float4 a = *(const float4*)&mix[(r0 + i) * 68 + k];
            c[i][0] = fmaf(a.x, b0.x, fmaf(a.y, b1.x, fmaf(a.z, b2.x, fmaf(a.w, b3.x, c[i][0]))));
            c[i][1] = fmaf(a.x, b0.y, fmaf(a.y, b1.y, fmaf(a.z, b2.y, fmaf(a.w, b3.y, c[i][1]))));
            c[i][2] = fmaf(a.x, b0.z, fmaf(a.y, b1.z, fmaf(a.z, b2.z, fmaf(a.w, b3.z, c[i][2]))));
            c[i][3] = fmaf(a.x, b0.w, fmaf(a.y, b1.w, fmaf(a.z, b2.w, fmaf(a.w, b3.w, c[i][3]))));
        }
    }
#pragma unroll
    for (int i = 0; i < 2; i++) {
        int n2 = perm[wslot + r0 + i];
        float sc = 1.0f;
        if (scaled) sc = dinv[n2];
        store_h4(&hout[(size_t)n2 * NHID + o0],
                 fmaxf(c[i][0], 0.f) * sc, fmaxf(c[i][1], 0.f) * sc,
                 fmaxf(c[i][2], 0.f) * sc, fmaxf(c[i][3], 0.f) * sc);
    }
}

// ---------------- fc2: out = h @ fc2_w^T + b (h in fp16) ----------------

__global__ __launch_bounds__(256) void k_fc2(const __half* __restrict__ h,
                                             const float* __restrict__ w,
                                             const float* __restrict__ b,
                                             float* __restrict__ out) {
    __shared__ float wT[NHID * 44];
    __shared__ float hsl[64 * 68];
    int t = threadIdx.x;
    int nodeBase = blockIdx.x * 64;

    for (int id = t; id < NHID * OUT_CH; id += 256) {
        int o = id >> 6, k = id & 63;
        wT[k * 44 + o] = w[id];
    }
    {
        int nl = t >> 2, seg = t & 3;
        int n = nodeBase + nl;
        float* dst = hsl + nl * 68 + seg * 16;
        if (n < N_NODES) {
            float4 raw0 = *(const float4*)&h[(size_t)n * NHID + seg * 16];
            float4 raw1 = *(const float4*)&h[(size_t)n * NHID + seg * 16 + 8];
            const __half2* hp0 = (const __half2*)&raw0;
            const __half2* hp1 = (const __half2*)&raw1;
#pragma unroll
            for (int q = 0; q < 4; q++) {
                float2 f = __half22float2(hp0[q]);
                dst[q * 2 + 0] = f.x;
                dst[q * 2 + 1] = f.y;
            }
#pragma unroll
            for (int q = 0; q < 4; q++) {
                float2 f = __half22float2(hp1[q]);
                dst[8 + q * 2 + 0] = f.x;
                dst[8 + q * 2 + 1] = f.y;
            }
        } else {
#pragma unroll
            for (int q = 0; q < 16; q++) dst[q] = 0.f;
        }
    }
    __syncthreads();

    if (t < 160) {
        int tx = t % 10, ty = t / 10;
        int o0 = tx * 4, n0 = ty * 4;
        float c[4][4];
#pragma unroll
        for (int i = 0; i < 4; i++)
#pragma unroll
            for (int j = 0; j < 4; j++) c[i][j] = 0.f;

#pragma unroll 4
        for (int k = 0; k < NHID; k += 4) {
            float4 b0 = *(const float4*)&wT[(k + 0) * 44 + o0];
            float4 b1 = *(const float4*)&wT[(k + 1) * 44 + o0];
            float4 b2 = *(const float4*)&wT[(k + 2) * 44 + o0];
            float4 b3 = *(const float4*)&wT[(k + 3) * 44 + o0];
#pragma unroll
            for (int i = 0; i < 4; i++) {
                float4 a = *(const float4*)&hsl[(n0 + i) * 68 + k];
                c[i][0] = fmaf(a.x, b0.x, fmaf(a.y, b1.x, fmaf(a.z, b2.x, fmaf(a.w, b3.x, c[i][0]))));
                c[i][1] = fmaf(a.x, b0.y, fmaf(a.y, b1.y, fmaf(a.z, b2.y, fmaf(a.w, b3.y, c[i][1]))));
                c[i][2] = fmaf(a.x, b0.z, fmaf(a.y, b1.z, fmaf(a.z, b2.z, fmaf(a.w, b3.z, c[i][2]))));
                c[i][3] = fmaf(a.x, b0.w, fmaf(a.y, b1.w, fmaf(a.z, b2.w, fmaf(a.w, b3.w, c[i][3]))));
            }
        }
        float4 bias = *(const float4*)&b[o0];
#pragma unroll
        for (int i = 0; i < 4; i++) {
            int n = nodeBase + n0 + i;
            if (n < N_NODES) {
                float4 v;
                v.x = c[i][0] + bias.x;
                v.y = c[i][1] + bias.y;
                v.z = c[i][2] + bias.z;
                v.w = c[i][3] + bias.w;
                *(float4*)&out[(size_t)n * OUT_CH + o0] = v;
            }
        }
    }
}

// ---------------- launch ----------------

extern "C" void kernel_launch(void* const* d_in, const int* in_sizes, int n_in,
                              void* d_out, int out_size, void* d_ws, size_t ws_size,
                              hipStream_t stream) {
    const float* x    = (const float*)d_in[0];
    const int*   ei   = (const int*)d_in[1];
    const float* fc1w = (const float*)d_in[3];
    const float* fc1b = (const float*)d_in[4];
    const float* cw   = (const float*)d_in[5];
    const float* fc2w = (const float*)d_in[6];
    const float* fc2b = (const float*)d_in[7];
    float* out = (float*)d_out;

    char* p = (char*)d_ws;
    auto alloc = [&](size_t bytes) { char* r = p; p += (bytes + 255) & ~(size_t)255; return r; };
    __half* h016   = (__half*)alloc((size_t)N_NODES * NHID * 2);
    __half* hsA    = (__half*)alloc((size_t)(N_NODES + 1) * NHID * 2);   // +1 zero row
    __half* hsB    = (__half*)alloc((size_t)(N_NODES + 1) * NHID * 2);   // +1 zero row
    int*    e4     = (int*)   alloc((size_t)E4CAP * 4);                  // padded CSR
    int2*   ebufA  = (int2*)  alloc((size_t)NBUCK * BCAP * 8);   // 14.05 MB; reused as h4 buffer
    int*    cnt    = (int*)   alloc((size_t)N_NODES * 4);
    int*    rowptr = (int*)   alloc((size_t)(N_NODES + 1) * 4);
    int*    perm   = (int*)   alloc((size_t)N_NODES * 4);
    int*    bCnt   = (int*)   alloc((size_t)NBUCK * 4);
    float*  dinv   = (float*) alloc((size_t)N_NODES * 4);
    int*    bsum   = (int*)   alloc(512 * 4);
    __half* h4     = (__half*)ebufA;    // layer-4 unscaled output (after scatB consumed ebufA)

    hipMemsetAsync(bCnt, 0, (size_t)NBUCK * 4, stream);
    hipMemsetAsync(hsA + (size_t)N_NODES * NHID, 0, NHID * 2, stream);
    hipMemsetAsync(hsB + (size_t)N_NODES * NHID, 0, NHID * 2, stream);

    k_scatA  <<<(N_EDGES + 4095) / 4096, 256, 0, stream>>>(ei, bCnt, ebufA);
    k_deg    <<<NBUCK, 256, 0, stream>>>(ebufA, bCnt, cnt);
    k_place32<<<NBLK, 256, 0, stream>>>(cnt, perm);
    k_scan1  <<<NBLK, 256, 0, stream>>>(cnt, rowptr, bsum, dinv);
    k_scan2  <<<1, 512, 0, stream>>>(bsum, rowptr);
    k_scan3  <<<NBLK, 256, 0, stream>>>(bsum, rowptr);
    k_scatB  <<<NBUCK, 256, 0, stream>>>(ebufA, bCnt, rowptr, e4);

    int gb64 = (N_NODES + 63) / 64;   // 1563
    int gb32 = N_NODES / 32;          // 3125
    k_fc1 <<<gb64, 256, 0, stream>>>(x, fc1w, fc1b, dinv, h016, hsA);
    k_conv<<<gb32, 256, 0, stream>>>(hsA, h016, rowptr, e4, cw + 0 * NHID * NHID, dinv, perm, hsB, 1);
    k_conv<<<gb32, 256, 0, stream>>>(hsB, h016, rowptr, e4, cw + 1 * NHID * NHID, dinv, perm, hsA, 1);
    k_conv<<<gb32, 256, 0, stream>>>(hsA, h016, rowptr, e4, cw + 2 * NHID * NHID, dinv, perm, hsB, 1);
    k_conv<<<gb32, 256, 0, stream>>>(hsB, h016, rowptr, e4, cw + 3 * NHID * NHID, dinv, perm, h4, 0);
    k_fc2 <<<gb64, 256, 0, stream>>>(h4, fc2w, fc2b, out);
}

// Round 11
// 406.072 us; speedup vs baseline: 2.3186x; 2.2949x over previous
//
#include <hip/hip_runtime.h>
#include <hip/hip_fp16.h>

#define N_NODES 100000
#define N_EDGES 1600000
#define IN_CH   128
#define NHID    64
#define OUT_CH  40
#define NBLK    391    // ceil(N_NODES/256)
#define NBUCK   196    // ceil(N_NODES/512)
#define BCAP    8960   // fixed bucket capacity (mean 8163, +8 sigma)
#define E4CAP   (N_EDGES + 7 * N_NODES + 64)   // padded CSR worst case

// ---------------- rowptr scans (over PADDED counts; dinv from true counts) ----------------

__global__ __launch_bounds__(256) void k_scan1(const int* __restrict__ cnt,
                                               int* __restrict__ rowptr,
                                               int* __restrict__ bsum,
                                               float* __restrict__ dinv) {
    __shared__ int s[256];
    int t = threadIdx.x;
    int n = blockIdx.x * 256 + t;
    int v = (n < N_NODES) ? cnt[n] : 0;
    int pv = (v + 7) & ~7;                  // pad to multiple of 8
    s[t] = pv;
    __syncthreads();
    for (int off = 1; off < 256; off <<= 1) {
        int add = (t >= off) ? s[t - off] : 0;
        __syncthreads();
        s[t] += add;
        __syncthreads();
    }
    int incl = s[t];
    if (n < N_NODES) {
        rowptr[n] = incl - pv;
        dinv[n] = (v > 0) ? rsqrtf((float)v) : 0.0f;
    }
    if (t == 255) bsum[blockIdx.x] = incl;
}

__global__ __launch_bounds__(512) void k_scan2(int* __restrict__ bsum,
                                               int* __restrict__ rowptr) {
    __shared__ int s[512];
    int t = threadIdx.x;
    int v = (t < NBLK) ? bsum[t] : 0;
    s[t] = v;
    __syncthreads();
    for (int off = 1; off < 512; off <<= 1) {
        int add = (t >= off) ? s[t - off] : 0;
        __syncthreads();
        s[t] += add;
        __syncthreads();
    }
    if (t == NBLK - 1) rowptr[N_NODES] = s[t];   // padded grand total
    if (t < NBLK) bsum[t] = s[t] - v;
}

__global__ __launch_bounds__(256) void k_scan3(const int* __restrict__ bsum,
                                               int* __restrict__ rowptr) {
    int n = blockIdx.x * 256 + threadIdx.x;
    if (n < N_NODES) rowptr[n] = rowptr[n] + bsum[n >> 8];
}

// ---- BLOCK-LOCAL degree sort: rank the 32 nodes of each conv window ----
// perm[g0 + rank] = n, rank = #{j in window : deg[j] < deg[n] or (== and j<n)}.
// Bijective within the window; preserves R7 memory locality (perm stays inside
// the same 32-node window). No atomics, deterministic. N_NODES%32==0.

__global__ __launch_bounds__(256) void k_place32(const int* __restrict__ cnt,
                                                 int* __restrict__ perm) {
    int n = blockIdx.x * 256 + threadIdx.x;
    if (n < N_NODES) {
        int g0 = n & ~31;
        int dn = cnt[n];
        int rank = 0;
#pragma unroll 8
        for (int j = 0; j < 32; j++) {
            int dj = cnt[g0 + j];
            rank += (dj < dn || (dj == dn && (g0 + j) < n)) ? 1 : 0;
        }
        perm[g0 + rank] = n;
    }
}

// ---- scatter pass A: fixed-capacity buckets by c>>9 (pure bucketing; R5-proven) ----

__global__ __launch_bounds__(256) void k_scatA(const int* __restrict__ ei,
                                               int* __restrict__ bucketCnt,
                                               int2* __restrict__ ebufA) {
    __shared__ int hist[NBUCK];
    __shared__ int base[NBUCK];
    int t = threadIdx.x;
    int chunk = blockIdx.x * 4096;
    for (int i = t; i < NBUCK; i += 256) hist[i] = 0;
    __syncthreads();
#pragma unroll 4
    for (int i = 0; i < 16; i++) {
        int e = chunk + i * 256 + t;
        if (e < N_EDGES) atomicAdd(&hist[ei[N_EDGES + e] >> 9], 1);
    }
    __syncthreads();
    for (int b = t; b < NBUCK; b += 256) {
        int h = hist[b];
        base[b] = h ? atomicAdd(&bucketCnt[b], h) : 0;
    }
    __syncthreads();
#pragma unroll 4
    for (int i = 0; i < 16; i++) {
        int e = chunk + i * 256 + t;
        if (e < N_EDGES) {
            int r = ei[e], c = ei[N_EDGES + e];
            int pos = atomicAdd(&base[c >> 9], 1);
            ebufA[(size_t)(c >> 9) * BCAP + pos] = make_int2(r, c);
        }
    }
}

// ---- degree count from bucketed edges: contiguous read, LDS histogram ----

__global__ __launch_bounds__(256) void k_deg(const int2* __restrict__ ebufA,
                                             const int* __restrict__ bucketCnt,
                                             int* __restrict__ cnt) {
    __shared__ int hist[512];
    int b = blockIdx.x;
    int nodeB = b * 512;
    int t = threadIdx.x;
    for (int i = t; i < 512; i += 256) hist[i] = 0;
    __syncthreads();
    int nE = bucketCnt[b];
    const int2* src = ebufA + (size_t)b * BCAP;
    for (int i = t; i < nE; i += 256) atomicAdd(&hist[src[i].y - nodeB], 1);
    __syncthreads();
    for (int i = t; i < 512; i += 256) {
        int node = nodeB + i;
        if (node < N_NODES) cnt[node] = hist[i];
    }
}

// ---- scatter pass B: per-NODE cursors -> padded CSR; tail-fill pads with zero row ----

__global__ __launch_bounds__(256) void k_scatB(const int2* __restrict__ ebufA,
                                               const int* __restrict__ bucketCnt,
                                               const int* __restrict__ rowptr,
                                               int* __restrict__ e4) {
    __shared__ int lcur[512];
    int b = blockIdx.x;
    int nodeB = b * 512;
    int t = threadIdx.x;
    for (int i = t; i < 512; i += 256) {
        int node = nodeB + i;
        lcur[i] = (node < N_NODES) ? rowptr[node] : 0;
    }
    __syncthreads();
    int nE = bucketCnt[b];
    const int2* src = ebufA + (size_t)b * BCAP;
    for (int i = t; i < nE; i += 256) {
        int2 rc = src[i];
        int pos = atomicAdd(&lcur[rc.y - nodeB], 1);
        e4[pos] = rc.x;
    }
    __syncthreads();
    for (int i = t; i < 512; i += 256) {
        int node = nodeB + i;
        if (node < N_NODES) {
            int end = rowptr[node + 1];
            for (int pos = lcur[i]; pos < end; pos++) e4[pos] = N_NODES;
        }
    }
}

// ---- pack 4 floats -> 4 halves (8B) ----
__device__ __forceinline__ void store_h4(__half* dst, float a, float b, float c, float d) {
    union { uint2 u; __half2 h[2]; } pk;
    pk.h[0] = __floats2half2_rn(a, b);
    pk.h[1] = __floats2half2_rn(c, d);
    *(uint2*)dst = pk.u;
}

// ---------------- fc1: retiled (nodes on ty, channels on tx) + W in LDS ----------------

__global__ __launch_bounds__(256, 2) void k_fc1(const float* __restrict__ x,
                                                const float* __restrict__ w,
                                                const float* __restrict__ b,
                                                const float* __restrict__ dinv,
                                                __half* __restrict__ h016,
                                                __half* __restrict__ hs1) {
    __shared__ float xs[64 * 128];     // [node row][f4idx ^ swz]
    __shared__ float wL[64 * 128];     // [out ch row][f4idx ^ swz]
    int t = threadIdx.x;
    int nodeBase = blockIdx.x * 64;

    {
        int lane8 = t & 7, rhalf = t >> 3;     // 32 rows per pass
#pragma unroll
        for (int r2 = 0; r2 < 2; r2++) {
            int nl = r2 * 32 + rhalf;
            int swz = (nl ^ (nl >> 3)) & 7;
            int n = nodeBase + nl;
            float4* dstrow = (float4*)(xs + nl * 128);
            if (n < N_NODES) {
                const float4* src = (const float4*)(x + (size_t)n * IN_CH);
#pragma unroll
                for (int q = 0; q < 4; q++) dstrow[(q * 8 + lane8) ^ swz] = src[q * 8 + lane8];
            } else {
                float4 z = {0.f, 0.f, 0.f, 0.f};
#pragma unroll
                for (int q = 0; q < 4; q++) dstrow[(q * 8 + lane8) ^ swz] = z;
            }
            float4* dstw = (float4*)(wL + nl * 128);
            const float4* srcw = (const float4*)(w + (size_t)nl * IN_CH);
#pragma unroll
            for (int q = 0; q < 4; q++) dstw[(q * 8 + lane8) ^ swz] = srcw[q * 8 + lane8];
        }
    }
    __syncthreads();

    int tx = t & 15, ty = t >> 4;
    int o0 = tx * 4, n0 = ty * 4;     // nodes on ty, channels on tx
    int swzA0 = ((n0 + 0) ^ ((n0 + 0) >> 3)) & 7;
    int swzA1 = ((n0 + 1) ^ ((n0 + 1) >> 3)) & 7;
    int swzA2 = ((n0 + 2) ^ ((n0 + 2) >> 3)) & 7;
    int swzA3 = ((n0 + 3) ^ ((n0 + 3) >> 3)) & 7;
    int swzW0 = ((o0 + 0) ^ ((o0 + 0) >> 3)) & 7;
    int swzW1 = ((o0 + 1) ^ ((o0 + 1) >> 3)) & 7;
    int swzW2 = ((o0 + 2) ^ ((o0 + 2) >> 3)) & 7;
    int swzW3 = ((o0 + 3) ^ ((o0 + 3) >> 3)) & 7;
    const float4* ar0 = (const float4*)(xs + (n0 + 0) * 128);
    const float4* ar1 = (const float4*)(xs + (n0 + 1) * 128);
    const float4* ar2 = (const float4*)(xs + (n0 + 2) * 128);
    const float4* ar3 = (const float4*)(xs + (n0 + 3) * 128);
    const float4* wr0 = (const float4*)(wL + (o0 + 0) * 128);
    const float4* wr1 = (const float4*)(wL + (o0 + 1) * 128);
    const float4* wr2 = (const float4*)(wL + (o0 + 2) * 128);
    const float4* wr3 = (const float4*)(wL + (o0 + 3) * 128);

    float c[4][4];
#pragma unroll
    for (int i = 0; i < 4; i++)
#pragma unroll
        for (int j = 0; j < 4; j++) c[i][j] = 0.f;

#pragma unroll 4
    for (int k = 0; k < IN_CH; k += 4) {
        int kk = k >> 2;
        float4 b0 = wr0[kk ^ swzW0];
        float4 b1 = wr1[kk ^ swzW1];
        float4 b2 = wr2[kk ^ swzW2];
        float4 b3 = wr3[kk ^ swzW3];
        float4 a0 = ar0[kk ^ swzA0];
        float4 a1 = ar1[kk ^ swzA1];
        float4 a2 = ar2[kk ^ swzA2];
        float4 a3 = ar3[kk ^ swzA3];
#pragma unroll
        for (int i = 0; i < 4; i++) {
            float4 a = (i == 0) ? a0 : (i == 1) ? a1 : (i == 2) ? a2 : a3;
            c[i][0] = fmaf(a.x, b0.x, fmaf(a.y, b0.y, fmaf(a.z, b0.z, fmaf(a.w, b0.w, c[i][0]))));
            c[i][1] = fmaf(a.x, b1.x, fmaf(a.y, b1.y, fmaf(a.z, b1.z, fmaf(a.w, b1.w, c[i][1]))));
            c[i][2] = fmaf(a.x, b2.x, fmaf(a.y, b2.y, fmaf(a.z, b2.z, fmaf(a.w, b2.w, c[i][2]))));
            c[i][3] = fmaf(a.x, b3.x, fmaf(a.y, b3.y, fmaf(a.z, b3.z, fmaf(a.w, b3.w, c[i][3]))));
        }
    }

    float4 bias = *(const float4*)&b[o0];
#pragma unroll
    for (int i = 0; i < 4; i++) {
        int n = nodeBase + n0 + i;
        if (n < N_NODES) {
            float vx = fmaxf(c[i][0] + bias.x, 0.f);
            float vy = fmaxf(c[i][1] + bias.y, 0.f);
            float vz = fmaxf(c[i][2] + bias.z, 0.f);
            float vw = fmaxf(c[i][3] + bias.w, 0.f);
            store_h4(&h016[(size_t)n * NHID + o0], vx, vy, vz, vw);
            float dn = dinv[n];
            store_h4(&hs1[(size_t)n * NHID + o0], vx * dn, vy * dn, vz * dn, vw * dn);
        }
    }
}

// ------- fused GCN2Conv layer: wave-autonomous + block-local degree-sorted waves -------
// __launch_bounds__(256, 4): R8-R10's (256,8) capped VGPR at 32 -> the pipeline
// buffers (pvA/pvB = 32 VGPRs) spilled to scratch = 429MB WRITE/dispatch, 3.4x
// slowdown. (256,4) gives VGPR 64, zero spill (R7-proven).

__global__ __launch_bounds__(256, 4) void k_conv(const __half* __restrict__ hs,
                                                 const __half* __restrict__ h0,
                                                 const int* __restrict__ rowptr,
                                                 const int* __restrict__ e4,
                                                 const float* __restrict__ W,   // [c][o] 64x64
                                                 const float* __restrict__ dinv,
                                                 const int* __restrict__ perm,
                                                 __half* __restrict__ hout,
                                                 int scaled) {
    __shared__ float mixs[4][8 * 68];
    int t = threadIdx.x;
    int wid = t >> 6, lane = t & 63;
    int wslot = blockIdx.x * 32 + wid * 8;   // 8 perm slots per wave (within block window)
    int grp = lane >> 3;                     // 8 groups of 8 lanes -> 1 node each
    int cg = (lane & 7) * 8;                 // 8 channels per lane
    float* mix = mixs[wid];

    int n = perm[wslot + grp];
    int s = rowptr[n], e = rowptr[n + 1];    // e-s is a multiple of 8

#define ISSUE(pv, pm)                                                    \
    {                                                                    \
        pv[0] = *(const float4*)&hs[(size_t)pm.x * NHID + cg];           \
        pv[1] = *(const float4*)&hs[(size_t)pm.y * NHID + cg];           \
        pv[2] = *(const float4*)&hs[(size_t)pm.z * NHID + cg];           \
        pv[3] = *(const float4*)&hs[(size_t)pm.w * NHID + cg];           \
    }
#define ACC4(cv)                                                         \
    {                                                                    \
        _Pragma("unroll")                                                \
        for (int u = 0; u < 4; u++) {                                    \
            const __half2* hp = (const __half2*)&cv[u];                  \
            _Pragma("unroll")                                            \
            for (int q = 0; q < 4; q++) {                                \
                float2 f = __half22float2(hp[q]);                        \
                acc[q * 2 + 0] += f.x;                                   \
                acc[q * 2 + 1] += f.y;                                   \
            }                                                            \
        }                                                                \
    }

    int4   pmA, pmB;
    float4 pvA[4], pvB[4];
    if (e > s) {                              // deg >= 8 when nonzero (padded)
        pmA = *(const int4*)&e4[s];
        ISSUE(pvA, pmA);
        pmB = *(const int4*)&e4[s + 4];
        ISSUE(pvB, pmB);
    }

    float dn = dinv[n];
    float4 h0raw = *(const float4*)&h0[(size_t)n * NHID + cg];   // 8 halves

    float acc[8];
#pragma unroll
    for (int i = 0; i < 8; i++) acc[i] = 0.f;

    for (int j = s; j < e; j += 8) {
        {
            float4 cv[4];
#pragma unroll
            for (int u = 0; u < 4; u++) cv[u] = pvA[u];
            int jn = j + 8;
            if (jn < e) { pmA = *(const int4*)&e4[jn]; ISSUE(pvA, pmA); }
            ACC4(cv);
        }
        {
            float4 cv[4];
#pragma unroll
            for (int u = 0; u < 4; u++) cv[u] = pvB[u];
            int jn = j + 12;
            if (jn < e) { pmB = *(const int4*)&e4[jn]; ISSUE(pvB, pmB); }
            ACC4(cv);
        }
    }
#undef ISSUE
#undef ACC4

    {
        const __half* h0h = (const __half*)&h0raw;
        float a = 0.9f * dn;
        float m[8];
#pragma unroll
        for (int q = 0; q < 8; q++)
            m[q] = fmaf(a, acc[q], 0.1f * __half2float(h0h[q]));
        float4 m0 = {m[0], m[1], m[2], m[3]};
        float4 m1 = {m[4], m[5], m[6], m[7]};
        *(float4*)&mix[grp * 68 + cg] = m0;
        *(float4*)&mix[grp * 68 + cg + 4] = m1;
    }
    __threadfence_block();   // mix visible within wave

    // per-wave GEMM 8x64, 2x4 acc per lane; W rows broadcast via L1; fp16 output
    int tx = lane & 15, ty = lane >> 4;
    int o0 = tx * 4, r0 = ty * 2;
    float c[2][4];
#pragma unroll
    for (int i = 0; i < 2; i++)
#pragma unroll
        for (int j = 0; j < 4; j++) c[i][j] = 0.f;

#pragma unroll 4
    for (int k = 0; k < NHID; k += 4) {
        float4 b0 = *(const float4*)&W[(k + 0) * NHID + o0];
        float4 b1 = *(const float4*)&W[(k + 1) * NHID + o0];
        float4 b2 = *(const float4*)&W[(k + 2) * NHID + o0];
        float4 b3 = *(const float4*)&W[(k + 3) * NHID + o0];
#pragma unroll
        for (int i = 0; i < 2; i++) {
            float4 a = *(const float4*)&mix[(r0 + i) * 68 + k];
            c[i][0] = fmaf(a.x, b0.x, fmaf(a.y, b1.x, fmaf(a.z, b2.x, fmaf(a.w, b3.x, c[i][0]))));
            c[i][1] = fmaf(a.x, b0.y, fmaf(a.y, b1.y, fmaf(a.z, b2.y, fmaf(a.w, b3.y, c[i][1]))));
            c[i][2] = fmaf(a.x, b0.z, fmaf(a.y, b1.z, fmaf(a.z, b2.z, fmaf(a.w, b3.z, c[i][2]))));
            c[i][3] = fmaf(a.x, b0.w, fmaf(a.y, b1.w, fmaf(a.z, b2.w, fmaf(a.w, b3.w, c[i][3]))));
        }
    }
#pragma unroll
    for (int i = 0; i < 2; i++) {
        int n2 = perm[wslot + r0 + i];
        float sc = 1.0f;
        if (scaled) sc = dinv[n2];
        store_h4(&hout[(size_t)n2 * NHID + o0],
                 fmaxf(c[i][0], 0.f) * sc, fmaxf(c[i][1], 0.f) * sc,
                 fmaxf(c[i][2], 0.f) * sc, fmaxf(c[i][3], 0.f) * sc);
    }
}

// ---------------- fc2: out = h @ fc2_w^T + b (h in fp16) ----------------

__global__ __launch_bounds__(256) void k_fc2(const __half* __restrict__ h,
                                             const float* __restrict__ w,
                                             const float* __restrict__ b,
                                             float* __restrict__ out) {
    __shared__ float wT[NHID * 44];
    __shared__ float hsl[64 * 68];
    int t = threadIdx.x;
    int nodeBase = blockIdx.x * 64;

    for (int id = t; id < NHID * OUT_CH; id += 256) {
        int o = id >> 6, k = id & 63;
        wT[k * 44 + o] = w[id];
    }
    {
        int nl = t >> 2, seg = t & 3;
        int n = nodeBase + nl;
        float* dst = hsl + nl * 68 + seg * 16;
        if (n < N_NODES) {
            float4 raw0 = *(const float4*)&h[(size_t)n * NHID + seg * 16];
            float4 raw1 = *(const float4*)&h[(size_t)n * NHID + seg * 16 + 8];
            const __half2* hp0 = (const __half2*)&raw0;
            const __half2* hp1 = (const __half2*)&raw1;
#pragma unroll
            for (int q = 0; q < 4; q++) {
                float2 f = __half22float2(hp0[q]);
                dst[q * 2 + 0] = f.x;
                dst[q * 2 + 1] = f.y;
            }
#pragma unroll
            for (int q = 0; q < 4; q++) {
                float2 f = __half22float2(hp1[q]);
                dst[8 + q * 2 + 0] = f.x;
                dst[8 + q * 2 + 1] = f.y;
            }
        } else {
#pragma unroll
            for (int q = 0; q < 16; q++) dst[q] = 0.f;
        }
    }
    __syncthreads();

    if (t < 160) {
        int tx = t % 10, ty = t / 10;
        int o0 = tx * 4, n0 = ty * 4;
        float c[4][4];
#pragma unroll
        for (int i = 0; i < 4; i++)
#pragma unroll
            for (int j = 0; j < 4; j++) c[i][j] = 0.f;

#pragma unroll 4
        for (int k = 0; k < NHID; k += 4) {
            float4 b0 = *(const float4*)&wT[(k + 0) * 44 + o0];
            float4 b1 = *(const float4*)&wT[(k + 1) * 44 + o0];
            float4 b2 = *(const float4*)&wT[(k + 2) * 44 + o0];
            float4 b3 = *(const float4*)&wT[(k + 3) * 44 + o0];
#pragma unroll
            for (int i = 0; i < 4; i++) {
                float4 a = *(const float4*)&hsl[(n0 + i) * 68 + k];
                c[i][0] = fmaf(a.x, b0.x, fmaf(a.y, b1.x, fmaf(a.z, b2.x, fmaf(a.w, b3.x, c[i][0]))));
                c[i][1] = fmaf(a.x, b0.y, fmaf(a.y, b1.y, fmaf(a.z, b2.y, fmaf(a.w, b3.y, c[i][1]))));
                c[i][2] = fmaf(a.x, b0.z, fmaf(a.y, b1.z, fmaf(a.z, b2.z, fmaf(a.w, b3.z, c[i][2]))));
                c[i][3] = fmaf(a.x, b0.w, fmaf(a.y, b1.w, fmaf(a.z, b2.w, fmaf(a.w, b3.w, c[i][3]))));
            }
        }
        float4 bias = *(const float4*)&b[o0];
#pragma unroll
        for (int i = 0; i < 4; i++) {
            int n = nodeBase + n0 + i;
            if (n < N_NODES) {
                float4 v;
                v.x = c[i][0] + bias.x;
                v.y = c[i][1] + bias.y;
                v.z = c[i][2] + bias.z;
                v.w = c[i][3] + bias.w;
                *(float4*)&out[(size_t)n * OUT_CH + o0] = v;
            }
        }
    }
}

// ---------------- launch ----------------

extern "C" void kernel_launch(void* const* d_in, const int* in_sizes, int n_in,
                              void* d_out, int out_size, void* d_ws, size_t ws_size,
                              hipStream_t stream) {
    const float* x    = (const float*)d_in[0];
    const int*   ei   = (const int*)d_in[1];
    const float* fc1w = (const float*)d_in[3];
    const float* fc1b = (const float*)d_in[4];
    const float* cw   = (const float*)d_in[5];
    const float* fc2w = (const float*)d_in[6];
    const float* fc2b = (const float*)d_in[7];
    float* out = (float*)d_out;

    char* p = (char*)d_ws;
    auto alloc = [&](size_t bytes) { char* r = p; p += (bytes + 255) & ~(size_t)255; return r; };
    __half* h016   = (__half*)alloc((size_t)N_NODES * NHID * 2);
    __half* hsA    = (__half*)alloc((size_t)(N_NODES + 1) * NHID * 2);   // +1 zero row
    __half* hsB    = (__half*)alloc((size_t)(N_NODES + 1) * NHID * 2);   // +1 zero row
    int*    e4     = (int*)   alloc((size_t)E4CAP * 4);                  // padded CSR
    int2*   ebufA  = (int2*)  alloc((size_t)NBUCK * BCAP * 8);   // 14.05 MB; reused as h4 buffer
    int*    cnt    = (int*)   alloc((size_t)N_NODES * 4);
    int*    rowptr = (int*)   alloc((size_t)(N_NODES + 1) * 4);
    int*    perm   = (int*)   alloc((size_t)N_NODES * 4);
    int*    bCnt   = (int*)   alloc((size_t)NBUCK * 4);
    float*  dinv   = (float*) alloc((size_t)N_NODES * 4);
    int*    bsum   = (int*)   alloc(512 * 4);
    __half* h4     = (__half*)ebufA;    // layer-4 unscaled output (after scatB consumed ebufA)

    hipMemsetAsync(bCnt, 0, (size_t)NBUCK * 4, stream);
    hipMemsetAsync(hsA + (size_t)N_NODES * NHID, 0, NHID * 2, stream);
    hipMemsetAsync(hsB + (size_t)N_NODES * NHID, 0, NHID * 2, stream);

    k_scatA  <<<(N_EDGES + 4095) / 4096, 256, 0, stream>>>(ei, bCnt, ebufA);
    k_deg    <<<NBUCK, 256, 0, stream>>>(ebufA, bCnt, cnt);
    k_place32<<<NBLK, 256, 0, stream>>>(cnt, perm);
    k_scan1  <<<NBLK, 256, 0, stream>>>(cnt, rowptr, bsum, dinv);
    k_scan2  <<<1, 512, 0, stream>>>(bsum, rowptr);
    k_scan3  <<<NBLK, 256, 0, stream>>>(bsum, rowptr);
    k_scatB  <<<NBUCK, 256, 0, stream>>>(ebufA, bCnt, rowptr, e4);

    int gb64 = (N_NODES + 63) / 64;   // 1563
    int gb32 = N_NODES / 32;          // 3125
    k_fc1 <<<gb64, 256, 0, stream>>>(x, fc1w, fc1b, dinv, h016, hsA);
    k_conv<<<gb32, 256, 0, stream>>>(hsA, h016, rowptr, e4, cw + 0 * NHID * NHID, dinv, perm, hsB, 1);
    k_conv<<<gb32, 256, 0, stream>>>(hsB, h016, rowptr, e4, cw + 1 * NHID * NHID, dinv, perm, hsA, 1);
    k_conv<<<gb32, 256, 0, stream>>>(hsA, h016, rowptr, e4, cw + 2 * NHID * NHID, dinv, perm, hsB, 1);
    k_conv<<<gb32, 256, 0, stream>>>(hsB, h016, rowptr, e4, cw + 3 * NHID * NHID, dinv, perm, h4, 0);
    k_fc2 <<<gb64, 256, 0, stream>>>(h4, fc2w, fc2b, out);
}

// Round 12
// 396.071 us; speedup vs baseline: 2.3772x; 1.0253x over previous
//
#include <hip/hip_runtime.h>
#include <hip/hip_fp16.h>

#define N_NODES 100000
#define N_EDGES 1600000
#define IN_CH   128
#define NHID    64
#define OUT_CH  40
#define NBLK    391    // ceil(N_NODES/256)
#define NBUCK   196    // ceil(N_NODES/512)
#define BCAP    8960   // fixed bucket capacity (mean 8163, +8 sigma)
#define E4CAP   (N_EDGES + 7 * N_NODES + 64)   // padded CSR worst case

// ---------------- rowptr scans (over PADDED counts; dinv from true counts) ----------------

__global__ __launch_bounds__(256) void k_scan1(const int* __restrict__ cnt,
                                               int* __restrict__ rowptr,
                                               int* __restrict__ bsum,
                                               float* __restrict__ dinv) {
    __shared__ int s[256];
    int t = threadIdx.x;
    int n = blockIdx.x * 256 + t;
    int v = (n < N_NODES) ? cnt[n] : 0;
    int pv = (v + 7) & ~7;                  // pad to multiple of 8
    s[t] = pv;
    __syncthreads();
    for (int off = 1; off < 256; off <<= 1) {
        int add = (t >= off) ? s[t - off] : 0;
        __syncthreads();
        s[t] += add;
        __syncthreads();
    }
    int incl = s[t];
    if (n < N_NODES) {
        rowptr[n] = incl - pv;
        dinv[n] = (v > 0) ? rsqrtf((float)v) : 0.0f;
    }
    if (t == 255) bsum[blockIdx.x] = incl;
}

__global__ __launch_bounds__(512) void k_scan2(int* __restrict__ bsum,
                                               int* __restrict__ rowptr) {
    __shared__ int s[512];
    int t = threadIdx.x;
    int v = (t < NBLK) ? bsum[t] : 0;
    s[t] = v;
    __syncthreads();
    for (int off = 1; off < 512; off <<= 1) {
        int add = (t >= off) ? s[t - off] : 0;
        __syncthreads();
        s[t] += add;
        __syncthreads();
    }
    if (t == NBLK - 1) rowptr[N_NODES] = s[t];   // padded grand total
    if (t < NBLK) bsum[t] = s[t] - v;
}

__global__ __launch_bounds__(256) void k_scan3(const int* __restrict__ bsum,
                                               int* __restrict__ rowptr) {
    int n = blockIdx.x * 256 + threadIdx.x;
    if (n < N_NODES) rowptr[n] = rowptr[n] + bsum[n >> 8];
}

// ---- BLOCK-LOCAL degree sort: rank the 32 nodes of each conv window ----

__global__ __launch_bounds__(256) void k_place32(const int* __restrict__ cnt,
                                                 int* __restrict__ perm) {
    int n = blockIdx.x * 256 + threadIdx.x;
    if (n < N_NODES) {
        int g0 = n & ~31;
        int dn = cnt[n];
        int rank = 0;
#pragma unroll 8
        for (int j = 0; j < 32; j++) {
            int dj = cnt[g0 + j];
            rank += (dj < dn || (dj == dn && (g0 + j) < n)) ? 1 : 0;
        }
        perm[g0 + rank] = n;
    }
}

// ---- scatter pass A: fixed-capacity buckets by c>>9; PACKED entries ----
// entry = (r << 9) | (c & 511): r < 2^17, bucket-local c is 9 bits.
// Halves ebufA write traffic (12.8 -> 6.4 MB) and the deg/scatB re-reads.

__global__ __launch_bounds__(256) void k_scatA(const int* __restrict__ ei,
                                               int* __restrict__ bucketCnt,
                                               int* __restrict__ ebufA) {
    __shared__ int hist[NBUCK];
    __shared__ int base[NBUCK];
    int t = threadIdx.x;
    int chunk = blockIdx.x * 4096;
    for (int i = t; i < NBUCK; i += 256) hist[i] = 0;
    __syncthreads();
#pragma unroll 4
    for (int i = 0; i < 16; i++) {
        int e = chunk + i * 256 + t;
        if (e < N_EDGES) atomicAdd(&hist[ei[N_EDGES + e] >> 9], 1);
    }
    __syncthreads();
    for (int b = t; b < NBUCK; b += 256) {
        int h = hist[b];
        base[b] = h ? atomicAdd(&bucketCnt[b], h) : 0;
    }
    __syncthreads();
#pragma unroll 4
    for (int i = 0; i < 16; i++) {
        int e = chunk + i * 256 + t;
        if (e < N_EDGES) {
            int r = ei[e], c = ei[N_EDGES + e];
            int pos = atomicAdd(&base[c >> 9], 1);
            ebufA[(size_t)(c >> 9) * BCAP + pos] = (r << 9) | (c & 511);
        }
    }
}

// ---- degree count from bucketed edges: contiguous read, LDS histogram ----

__global__ __launch_bounds__(256) void k_deg(const int* __restrict__ ebufA,
                                             const int* __restrict__ bucketCnt,
                                             int* __restrict__ cnt) {
    __shared__ int hist[512];
    int b = blockIdx.x;
    int nodeB = b * 512;
    int t = threadIdx.x;
    for (int i = t; i < 512; i += 256) hist[i] = 0;
    __syncthreads();
    int nE = bucketCnt[b];
    const int* src = ebufA + (size_t)b * BCAP;
    for (int i = t; i < nE; i += 256) atomicAdd(&hist[src[i] & 511], 1);
    __syncthreads();
    for (int i = t; i < 512; i += 256) {
        int node = nodeB + i;
        if (node < N_NODES) cnt[node] = hist[i];
    }
}

// ---- scatter pass B: per-NODE cursors -> padded CSR; tail-fill pads with zero row ----

__global__ __launch_bounds__(256) void k_scatB(const int* __restrict__ ebufA,
                                               const int* __restrict__ bucketCnt,
                                               const int* __restrict__ rowptr,
                                               int* __restrict__ e4) {
    __shared__ int lcur[512];
    int b = blockIdx.x;
    int nodeB = b * 512;
    int t = threadIdx.x;
    for (int i = t; i < 512; i += 256) {
        int node = nodeB + i;
        lcur[i] = (node < N_NODES) ? rowptr[node] : 0;
    }
    __syncthreads();
    int nE = bucketCnt[b];
    const int* src = ebufA + (size_t)b * BCAP;
    for (int i = t; i < nE; i += 256) {
        int p = src[i];
        int pos = atomicAdd(&lcur[p & 511], 1);
        e4[pos] = p >> 9;          // p >= 0, logical shift ok
    }
    __syncthreads();
    for (int i = t; i < 512; i += 256) {
        int node = nodeB + i;
        if (node < N_NODES) {
            int end = rowptr[node + 1];
            for (int pos = lcur[i]; pos < end; pos++) e4[pos] = N_NODES;
        }
    }
}

// ---- pack 4 floats -> 4 halves (8B) ----
__device__ __forceinline__ void store_h4(__half* dst, float a, float b, float c, float d) {
    union { uint2 u; __half2 h[2]; } pk;
    pk.h[0] = __floats2half2_rn(a, b);
    pk.h[1] = __floats2half2_rn(c, d);
    *(uint2*)dst = pk.u;
}

// ---------------- fc1: retiled (nodes on ty, channels on tx) + W in LDS ----------------

__global__ __launch_bounds__(256, 2) void k_fc1(const float* __restrict__ x,
                                                const float* __restrict__ w,
                                                const float* __restrict__ b,
                                                const float* __restrict__ dinv,
                                                __half* __restrict__ h016,
                                                __half* __restrict__ hs1) {
    __shared__ float xs[64 * 128];     // [node row][f4idx ^ swz]
    __shared__ float wL[64 * 128];     // [out ch row][f4idx ^ swz]
    int t = threadIdx.x;
    int nodeBase = blockIdx.x * 64;

    {
        int lane8 = t & 7, rhalf = t >> 3;     // 32 rows per pass
#pragma unroll
        for (int r2 = 0; r2 < 2; r2++) {
            int nl = r2 * 32 + rhalf;
            int swz = (nl ^ (nl >> 3)) & 7;
            int n = nodeBase + nl;
            float4* dstrow = (float4*)(xs + nl * 128);
            if (n < N_NODES) {
                const float4* src = (const float4*)(x + (size_t)n * IN_CH);
#pragma unroll
                for (int q = 0; q < 4; q++) dstrow[(q * 8 + lane8) ^ swz] = src[q * 8 + lane8];
            } else {
                float4 z = {0.f, 0.f, 0.f, 0.f};
#pragma unroll
                for (int q = 0; q < 4; q++) dstrow[(q * 8 + lane8) ^ swz] = z;
            }
            float4* dstw = (float4*)(wL + nl * 128);
            const float4* srcw = (const float4*)(w + (size_t)nl * IN_CH);
#pragma unroll
            for (int q = 0; q < 4; q++) dstw[(q * 8 + lane8) ^ swz] = srcw[q * 8 + lane8];
        }
    }
    __syncthreads();

    int tx = t & 15, ty = t >> 4;
    int o0 = tx * 4, n0 = ty * 4;     // nodes on ty, channels on tx
    int swzA0 = ((n0 + 0) ^ ((n0 + 0) >> 3)) & 7;
    int swzA1 = ((n0 + 1) ^ ((n0 + 1) >> 3)) & 7;
    int swzA2 = ((n0 + 2) ^ ((n0 + 2) >> 3)) & 7;
    int swzA3 = ((n0 + 3) ^ ((n0 + 3) >> 3)) & 7;
    int swzW0 = ((o0 + 0) ^ ((o0 + 0) >> 3)) & 7;
    int swzW1 = ((o0 + 1) ^ ((o0 + 1) >> 3)) & 7;
    int swzW2 = ((o0 + 2) ^ ((o0 + 2) >> 3)) & 7;
    int swzW3 = ((o0 + 3) ^ ((o0 + 3) >> 3)) & 7;
    const float4* ar0 = (const float4*)(xs + (n0 + 0) * 128);
    const float4* ar1 = (const float4*)(xs + (n0 + 1) * 128);
    const float4* ar2 = (const float4*)(xs + (n0 + 2) * 128);
    const float4* ar3 = (const float4*)(xs + (n0 + 3) * 128);
    const float4* wr0 = (const float4*)(wL + (o0 + 0) * 128);
    const float4* wr1 = (const float4*)(wL + (o0 + 1) * 128);
    const float4* wr2 = (const float4*)(wL + (o0 + 2) * 128);
    const float4* wr3 = (const float4*)(wL + (o0 + 3) * 128);

    float c[4][4];
#pragma unroll
    for (int i = 0; i < 4; i++)
#pragma unroll
        for (int j = 0; j < 4; j++) c[i][j] = 0.f;

#pragma unroll 4
    for (int k = 0; k < IN_CH; k += 4) {
        int kk = k >> 2;
        float4 b0 = wr0[kk ^ swzW0];
        float4 b1 = wr1[kk ^ swzW1];
        float4 b2 = wr2[kk ^ swzW2];
        float4 b3 = wr3[kk ^ swzW3];
        float4 a0 = ar0[kk ^ swzA0];
        float4 a1 = ar1[kk ^ swzA1];
        float4 a2 = ar2[kk ^ swzA2];
        float4 a3 = ar3[kk ^ swzA3];
#pragma unroll
        for (int i = 0; i < 4; i++) {
            float4 a = (i == 0) ? a0 : (i == 1) ? a1 : (i == 2) ? a2 : a3;
            c[i][0] = fmaf(a.x, b0.x, fmaf(a.y, b0.y, fmaf(a.z, b0.z, fmaf(a.w, b0.w, c[i][0]))));
            c[i][1] = fmaf(a.x, b1.x, fmaf(a.y, b1.y, fmaf(a.z, b1.z, fmaf(a.w, b1.w, c[i][1]))));
            c[i][2] = fmaf(a.x, b2.x, fmaf(a.y, b2.y, fmaf(a.z, b2.z, fmaf(a.w, b2.w, c[i][2]))));
            c[i][3] = fmaf(a.x, b3.x, fmaf(a.y, b3.y, fmaf(a.z, b3.z, fmaf(a.w, b3.w, c[i][3]))));
        }
    }

    float4 bias = *(const float4*)&b[o0];
#pragma unroll
    for (int i = 0; i < 4; i++) {
        int n = nodeBase + n0 + i;
        if (n < N_NODES) {
            float vx = fmaxf(c[i][0] + bias.x, 0.f);
            float vy = fmaxf(c[i][1] + bias.y, 0.f);
            float vz = fmaxf(c[i][2] + bias.z, 0.f);
            float vw = fmaxf(c[i][3] + bias.w, 0.f);
            store_h4(&h016[(size_t)n * NHID + o0], vx, vy, vz, vw);
            float dn = dinv[n];
            store_h4(&hs1[(size_t)n * NHID + o0], vx * dn, vy * dn, vz * dn, vw * dn);
        }
    }
}

// ------- fused GCN2Conv layer: wave-autonomous, block-sorted, 4-DEEP pipeline -------
// A-D buffer sets, 16 edges/iteration, refills issued one full iteration (~16
// edges of compute) ahead -> ~2x the latency coverage of the 2-deep loop.
// launch_bounds(256,3): VGPR cap ~170, expected use ~120 (residency still
// resource-determined; R10 lesson: (256,8) capped VGPR at 32 -> scratch spill).
// Prologue C/D clamped to min(s+8/12, e-4): deg-8 nodes and the CSR tail never
// read past scatB's writes; clamped loads are never ACC'd. All e4 reads stay
// 16B-aligned (every rowptr is a multiple of 8; jn steps by 4).

__global__ __launch_bounds__(256, 3) void k_conv(const __half* __restrict__ hs,
                                                 const __half* __restrict__ h0,
                                                 const int* __restrict__ rowptr,
                                                 const int* __restrict__ e4,
                                                 const float* __restrict__ W,   // [c][o] 64x64
                                                 const float* __restrict__ dinv,
                                                 const int* __restrict__ perm,
                                                 __half* __restrict__ hout,
                                                 int scaled) {
    __shared__ float mixs[4][8 * 68];
    int t = threadIdx.x;
    int wid = t >> 6, lane = t & 63;
    int wslot = blockIdx.x * 32 + wid * 8;   // 8 perm slots per wave (within block window)
    int grp = lane >> 3;                     // 8 groups of 8 lanes -> 1 node each
    int cg = (lane & 7) * 8;                 // 8 channels per lane
    float* mix = mixs[wid];

    int n = perm[wslot + grp];
    int s = rowptr[n], e = rowptr[n + 1];    // e-s is a multiple of 8

#define ISSUE(pv, pm)                                                    \
    {                                                                    \
        pv[0] = *(const float4*)&hs[(size_t)pm.x * NHID + cg];           \
        pv[1] = *(const float4*)&hs[(size_t)pm.y * NHID + cg];           \
        pv[2] = *(const float4*)&hs[(size_t)pm.z * NHID + cg];           \
        pv[3] = *(const float4*)&hs[(size_t)pm.w * NHID + cg];           \
    }
#define ACC4(cv)                                                         \
    {                                                                    \
        _Pragma("unroll")                                                \
        for (int u = 0; u < 4; u++) {                                    \
            const __half2* hp = (const __half2*)&cv[u];                  \
            _Pragma("unroll")                                            \
            for (int q = 0; q < 4; q++) {                                \
                float2 f = __half22float2(hp[q]);                        \
                acc[q * 2 + 0] += f.x;                                   \
                acc[q * 2 + 1] += f.y;                                   \
            }                                                            \
        }                                                                \
    }
#define STEP(pm, pv, joff, jref)                                         \
    {                                                                    \
        float4 cv[4];                                                    \
        _Pragma("unroll")                                                \
        for (int u = 0; u < 4; u++) cv[u] = pv[u];                       \
        int jn = (jref);                                                 \
        if (jn < e) { pm = *(const int4*)&e4[jn]; ISSUE(pv, pm); }       \
        ACC4(cv);                                                        \
    }

    int4   pmA, pmB, pmC, pmD;
    float4 pvA[4], pvB[4], pvC[4], pvD[4];
    if (e > s) {                              // deg >= 8 when nonzero (padded)
        pmA = *(const int4*)&e4[s];
        ISSUE(pvA, pmA);
        pmB = *(const int4*)&e4[s + 4];
        ISSUE(pvB, pmB);
        int c8  = min(s + 8,  e - 4);         // clamp: dup of valid edges, never ACC'd
        int c12 = min(s + 12, e - 4);
        pmC = *(const int4*)&e4[c8];
        ISSUE(pvC, pmC);
        pmD = *(const int4*)&e4[c12];
        ISSUE(pvD, pmD);
    }

    float dn = dinv[n];
    float4 h0raw = *(const float4*)&h0[(size_t)n * NHID + cg];   // 8 halves

    float acc[8];
#pragma unroll
    for (int i = 0; i < 8; i++) acc[i] = 0.f;

    for (int j = s; j < e; j += 16) {
        STEP(pmA, pvA, 0,  j + 16);
        STEP(pmB, pvB, 4,  j + 20);
        if (j + 8 < e)  STEP(pmC, pvC, 8,  j + 24);
        if (j + 12 < e) STEP(pmD, pvD, 12, j + 28);
    }
#undef ISSUE
#undef ACC4
#undef STEP

    {
        const __half* h0h = (const __half*)&h0raw;
        float a = 0.9f * dn;
        float m[8];
#pragma unroll
        for (int q = 0; q < 8; q++)
            m[q] = fmaf(a, acc[q], 0.1f * __half2float(h0h[q]));
        float4 m0 = {m[0], m[1], m[2], m[3]};
        float4 m1 = {m[4], m[5], m[6], m[7]};
        *(float4*)&mix[grp * 68 + cg] = m0;
        *(float4*)&mix[grp * 68 + cg + 4] = m1;
    }
    __threadfence_block();   // mix visible within wave

    // per-wave GEMM 8x64, 2x4 acc per lane; W rows broadcast via L1; fp16 output
    int tx = lane & 15, ty = lane >> 4;
    int o0 = tx * 4, r0 = ty * 2;
    float c[2][4];
#pragma unroll
    for (int i = 0; i < 2; i++)
#pragma unroll
        for (int j = 0; j < 4; j++) c[i][j] = 0.f;

#pragma unroll 4
    for (int k = 0; k < NHID; k += 4) {
        float4 b0 = *(const float4*)&W[(k + 0) * NHID + o0];
        float4 b1 = *(const float4*)&W[(k + 1) * NHID + o0];
        float4 b2 = *(const float4*)&W[(k + 2) * NHID + o0];
        float4 b3 = *(const float4*)&W[(k + 3) * NHID + o0];
#pragma unroll
        for (int i = 0; i < 2; i++) {
            float4 a = *(const float4*)&mix[(r0 + i) * 68 + k];
            c[i][0] = fmaf(a.x, b0.x, fmaf(a.y, b1.x, fmaf(a.z, b2.x, fmaf(a.w, b3.x, c[i][0]))));
            c[i][1] = fmaf(a.x, b0.y, fmaf(a.y, b1.y, fmaf(a.z, b2.y, fmaf(a.w, b3.y, c[i][1]))));
            c[i][2] = fmaf(a.x, b0.z, fmaf(a.y, b1.z, fmaf(a.z, b2.z, fmaf(a.w, b3.z, c[i][2]))));
            c[i][3] = fmaf(a.x, b0.w, fmaf(a.y, b1.w, fmaf(a.z, b2.w, fmaf(a.w, b3.w, c[i][3]))));
        }
    }
#pragma unroll
    for (int i = 0; i < 2; i++) {
        int n2 = perm[wslot + r0 + i];
        float sc = 1.0f;
        if (scaled) sc = dinv[n2];
        store_h4(&hout[(size_t)n2 * NHID + o0],
                 fmaxf(c[i][0], 0.f) * sc, fmaxf(c[i][1], 0.f) * sc,
                 fmaxf(c[i][2], 0.f) * sc, fmaxf(c[i][3], 0.f) * sc);
    }
}

// ---------------- fc2: out = h @ fc2_w^T + b (h in fp16) ----------------

__global__ __launch_bounds__(256) void k_fc2(const __half* __restrict__ h,
                                             const float* __restrict__ w,
                                             const float* __restrict__ b,
                                             float* __restrict__ out) {
    __shared__ float wT[NHID * 44];
    __shared__ float hsl[64 * 68];
    int t = threadIdx.x;
    int nodeBase = blockIdx.x * 64;

    for (int id = t; id < NHID * OUT_CH; id += 256) {
        int o = id >> 6, k = id & 63;
        wT[k * 44 + o] = w[id];
    }
    {
        int nl = t >> 2, seg = t & 3;
        int n = nodeBase + nl;
        float* dst = hsl + nl * 68 + seg * 16;
        if (n < N_NODES) {
            float4 raw0 = *(const float4*)&h[(size_t)n * NHID + seg * 16];
            float4 raw1 = *(const float4*)&h[(size_t)n * NHID + seg * 16 + 8];
            const __half2* hp0 = (const __half2*)&raw0;
            const __half2* hp1 = (const __half2*)&raw1;
#pragma unroll
            for (int q = 0; q < 4; q++) {
                float2 f = __half22float2(hp0[q]);
                dst[q * 2 + 0] = f.x;
                dst[q * 2 + 1] = f.y;
            }
#pragma unroll
            for (int q = 0; q < 4; q++) {
                float2 f = __half22float2(hp1[q]);
                dst[8 + q * 2 + 0] = f.x;
                dst[8 + q * 2 + 1] = f.y;
            }
        } else {
#pragma unroll
            for (int q = 0; q < 16; q++) dst[q] = 0.f;
        }
    }
    __syncthreads();

    if (t < 160) {
        int tx = t % 10, ty = t / 10;
        int o0 = tx * 4, n0 = ty * 4;
        float c[4][4];
#pragma unroll
        for (int i = 0; i < 4; i++)
#pragma unroll
            for (int j = 0; j < 4; j++) c[i][j] = 0.f;

#pragma unroll 4
        for (int k = 0; k < NHID; k += 4) {
            float4 b0 = *(const float4*)&wT[(k + 0) * 44 + o0];
            float4 b1 = *(const float4*)&wT[(k + 1) * 44 + o0];
            float4 b2 = *(const float4*)&wT[(k + 2) * 44 + o0];
            float4 b3 = *(const float4*)&wT[(k + 3) * 44 + o0];
#pragma unroll
            for (int i = 0; i < 4; i++) {
                float4 a = *(const float4*)&hsl[(n0 + i) * 68 + k];
                c[i][0] = fmaf(a.x, b0.x, fmaf(a.y, b1.x, fmaf(a.z, b2.x, fmaf(a.w, b3.x, c[i][0]))));
                c[i][1] = fmaf(a.x, b0.y, fmaf(a.y, b1.y, fmaf(a.z, b2.y, fmaf(a.w, b3.y, c[i][1]))));
                c[i][2] = fmaf(a.x, b0.z, fmaf(a.y, b1.z, fmaf(a.z, b2.z, fmaf(a.w, b3.z, c[i][2]))));
                c[i][3] = fmaf(a.x, b0.w, fmaf(a.y, b1.w, fmaf(a.z, b2.w, fmaf(a.w, b3.w, c[i][3]))));
            }
        }
        float4 bias = *(const float4*)&b[o0];
#pragma unroll
        for (int i = 0; i < 4; i++) {
            int n = nodeBase + n0 + i;
            if (n < N_NODES) {
                float4 v;
                v.x = c[i][0] + bias.x;
                v.y = c[i][1] + bias.y;
                v.z = c[i][2] + bias.z;
                v.w = c[i][3] + bias.w;
                *(float4*)&out[(size_t)n * OUT_CH + o0] = v;
            }
        }
    }
}

// ---------------- launch ----------------

extern "C" void kernel_launch(void* const* d_in, const int* in_sizes, int n_in,
                              void* d_out, int out_size, void* d_ws, size_t ws_size,
                              hipStream_t stream) {
    const float* x    = (const float*)d_in[0];
    const int*   ei   = (const int*)d_in[1];
    const float* fc1w = (const float*)d_in[3];
    const float* fc1b = (const float*)d_in[4];
    const float* cw   = (const float*)d_in[5];
    const float* fc2w = (const float*)d_in[6];
    const float* fc2b = (const float*)d_in[7];
    float* out = (float*)d_out;

    char* p = (char*)d_ws;
    auto alloc = [&](size_t bytes) { char* r = p; p += (bytes + 255) & ~(size_t)255; return r; };
    __half* h016   = (__half*)alloc((size_t)N_NODES * NHID * 2);
    __half* hsA    = (__half*)alloc((size_t)(N_NODES + 1) * NHID * 2);   // +1 zero row
    __half* hsB    = (__half*)alloc((size_t)(N_NODES + 1) * NHID * 2);   // +1 zero row
    int*    e4     = (int*)   alloc((size_t)E4CAP * 4);                  // padded CSR
    int*    ebufA  = (int*)   alloc((size_t)NBUCK * BCAP * 8);   // 14.05 MB alloc (packed uses half); reused as h4
    int*    cnt    = (int*)   alloc((size_t)N_NODES * 4);
    int*    rowptr = (int*)   alloc((size_t)(N_NODES + 1) * 4);
    int*    perm   = (int*)   alloc((size_t)N_NODES * 4);
    int*    bCnt   = (int*)   alloc((size_t)NBUCK * 4);
    float*  dinv   = (float*) alloc((size_t)N_NODES * 4);
    int*    bsum   = (int*)   alloc(512 * 4);
    __half* h4     = (__half*)ebufA;    // layer-4 unscaled output (after scatB consumed ebufA)

    hipMemsetAsync(bCnt, 0, (size_t)NBUCK * 4, stream);
    hipMemsetAsync(hsA + (size_t)N_NODES * NHID, 0, NHID * 2, stream);
    hipMemsetAsync(hsB + (size_t)N_NODES * NHID, 0, NHID * 2, stream);

    k_scatA  <<<(N_EDGES + 4095) / 4096, 256, 0, stream>>>(ei, bCnt, ebufA);
    k_deg    <<<NBUCK, 256, 0, stream>>>(ebufA, bCnt, cnt);
    k_place32<<<NBLK, 256, 0, stream>>>(cnt, perm);
    k_scan1  <<<NBLK, 256, 0, stream>>>(cnt, rowptr, bsum, dinv);
    k_scan2  <<<1, 512, 0, stream>>>(bsum, rowptr);
    k_scan3  <<<NBLK, 256, 0, stream>>>(bsum, rowptr);
    k_scatB  <<<NBUCK, 256, 0, stream>>>(ebufA, bCnt, rowptr, e4);

    int gb64 = (N_NODES + 63) / 64;   // 1563
    int gb32 = N_NODES / 32;          // 3125
    k_fc1 <<<gb64, 256, 0, stream>>>(x, fc1w, fc1b, dinv, h016, hsA);
    k_conv<<<gb32, 256, 0, stream>>>(hsA, h016, rowptr, e4, cw + 0 * NHID * NHID, dinv, perm, hsB, 1);
    k_conv<<<gb32, 256, 0, stream>>>(hsB, h016, rowptr, e4, cw + 1 * NHID * NHID, dinv, perm, hsA, 1);
    k_conv<<<gb32, 256, 0, stream>>>(hsA, h016, rowptr, e4, cw + 2 * NHID * NHID, dinv, perm, hsB, 1);
    k_conv<<<gb32, 256, 0, stream>>>(hsB, h016, rowptr, e4, cw + 3 * NHID * NHID, dinv, perm, h4, 0);
    k_fc2 <<<gb64, 256, 0, stream>>>(h4, fc2w, fc2b, out);
}